// Round 10
// baseline (2459.176 us; speedup 1.0000x reference)
//
#include <hip/hip_runtime.h>
#include <hip/hip_bf16.h>

namespace {

constexpr int kB  = 256;   // batch
constexpr int kP  = 256;   // proposals
constexpr int kT  = 32;    // words
constexpr int kNS = 31;    // steps = T-1
constexpr int kV  = 3433;  // vocab
constexpr int kH  = 512;   // hidden
constexpr int kE  = 300;   // embed
constexpr int kC  = 128;   // feat dim
constexpr int kG  = 1536;  // 3H

typedef __bf16 bf16x8 __attribute__((ext_vector_type(8)));
typedef float f32x4 __attribute__((ext_vector_type(4)));

__device__ __forceinline__ float fexp2(float x) {
  float r; asm("v_exp_f32 %0, %1" : "=v"(r) : "v"(x)); return r;
}
__device__ __forceinline__ float frcp(float x) {
  float r; asm("v_rcp_f32 %0, %1" : "=v"(r) : "v"(x)); return r;
}
__device__ __forceinline__ float ftanh(float x) {
  float e = fexp2(x * 2.8853900817779268f);   // e^(2x)
  return 1.0f - 2.0f * frcp(e + 1.0f);
}
__device__ __forceinline__ float fsigm(float x) {
  return frcp(1.0f + fexp2(x * -1.4426950408889634f));
}
__device__ __forceinline__ unsigned short f2bf(float f) {   // RNE bf16
  unsigned u = __float_as_uint(f);
  u += 0x7FFFu + ((u >> 16) & 1u);
  return (unsigned short)(u >> 16);
}
__device__ __forceinline__ float bf2f(unsigned short s) {
  return __uint_as_float((unsigned)s << 16);
}

// ---------------- one-time weight transposes (W[r][k] -> Wt[k*R + r]) -------
__global__ void k_transpose(const float* s0, const float* s1, const float* s2,
                            const float* s3, const float* s4, const float* s5,
                            const float* s6, const float* s7, const float* s8,
                            float* d0, float* d1, float* d2, float* d3,
                            float* d4, float* d5, float* d6, float* d7,
                            float* d8) {
  const float* src; float* dst; int R, Cd;
  switch (blockIdx.y) {
    case 0:  src = s0; dst = d0; R = 128;  Cd = 300; break;  // W_td3
    case 1:  src = s1; dst = d1; R = 128;  Cd = 512; break;  // W_td1
    case 2:  src = s2; dst = d2; R = 128;  Cd = 128; break;  // W_td
    case 3:  src = s3; dst = d3; R = 128;  Cd = 128; break;  // W_l1
    case 4:  src = s4; dst = d4; R = 128;  Cd = 512; break;  // W_l2
    case 5:  src = s5; dst = d5; R = 128;  Cd = 128; break;  // W_l
    case 6:  src = s6; dst = d6; R = 1536; Cd = 128; break;  // W1_ih
    case 7:  src = s7; dst = d7; R = 1536; Cd = 128; break;  // W2_ih
    default: src = s8; dst = d8; R = 512;  Cd = 512; break;  // W_hidd
  }
  int n = R * Cd;
  for (int i = blockIdx.x * blockDim.x + threadIdx.x; i < n;
       i += gridDim.x * blockDim.x) {
    int k = i / R, r = i - k * R;
    dst[i] = src[r * Cd + k];    // dst[k*R + r]
  }
}

// ---------------- bf16 copies of the loop-local transposed weights -----------
__global__ void k_tobf16(const float* s0, const float* s1, const float* s2,
                         const float* s3, const float* s4, const float* s5,
                         const float* s6, const float* s7,
                         unsigned short* d0, unsigned short* d1,
                         unsigned short* d2, unsigned short* d3,
                         unsigned short* d4, unsigned short* d5,
                         unsigned short* d6, unsigned short* d7) {
  const float* s; unsigned short* d; int n;
  switch (blockIdx.y) {
    case 0:  s = s0; d = d0; n = kC * kC; break;   // l1t
    case 1:  s = s1; d = d1; n = kH * kC; break;   // l2t
    case 2:  s = s2; d = d2; n = kC * kC; break;   // lt
    case 3:  s = s3; d = d3; n = kC * kG; break;   // iht2
    case 4:  s = s4; d = d4; n = kH * kH; break;   // whd_t
    case 5:  s = s5; d = d5; n = kH * kC; break;   // td1t
    case 6:  s = s6; d = d6; n = kC * kC; break;   // tdt
    default: s = s7; d = d7; n = kC * kG; break;   // iht1
  }
  for (int i = blockIdx.x * blockDim.x + threadIdx.x; i < n;
       i += gridDim.x * blockDim.x)
    d[i] = f2bf(s[i]);
}

// ---------------- one-time weight hi/lo bf16 splits --------------------------
__global__ void k_split(const float* s0, const float* s1, const float* s2,
                        const float* s3,
                        unsigned short* h0, unsigned short* l0,
                        unsigned short* h1, unsigned short* l1,
                        unsigned short* h2, unsigned short* l2,
                        unsigned short* h3, unsigned short* l3) {
  const float* s; unsigned short* h; unsigned short* l; int n;
  switch (blockIdx.y) {
    case 0:  s = s0; h = h0; l = l0; n = kG * kH; break;   // W1_hh
    case 1:  s = s1; h = h1; l = l1; n = kG * kH; break;   // W2_hh
    case 2:  s = s2; h = h2; l = l2; n = kV * kH; break;   // W_cls
    default: s = s3; h = h3; l = l3; n = kH * kC; break;   // W_feat
  }
  for (int i = blockIdx.x * blockDim.x + threadIdx.x; i < n;
       i += gridDim.x * blockDim.x) {
    float v = s[i];
    unsigned short hb = f2bf(v);
    h[i] = hb;
    l[i] = f2bf(v - bf2f(hb));
  }
}

// ---------------- init: td = t_feat @ W_td2^T ; zero h states ----------------
__global__ void k_init(const float* __restrict__ t_feat,
                       const float* __restrict__ W_td2,
                       float* __restrict__ td, float* __restrict__ h1,
                       float* __restrict__ h2,
                       unsigned short* __restrict__ h1h,
                       unsigned short* __restrict__ h1l,
                       unsigned short* __restrict__ h2h,
                       unsigned short* __restrict__ h2l) {
  int tid = blockIdx.x * 256 + threadIdx.x;  // 32768 threads
  int b = tid >> 7, c = tid & 127;
  const float* tf = t_feat + b * kC;
  const float* w  = W_td2 + c * kC;
  float acc = 0.f;
  for (int k = 0; k < kC; ++k) acc = fmaf(tf[k], w[k], acc);
  td[tid] = acc;
  for (int i = tid; i < kB * kH; i += (1 << 15)) {
    h1[i] = 0.f; h2[i] = 0.f;
    h1h[i] = 0; h1l[i] = 0; h2h[i] = 0; h2l[i] = 0;
  }
}

// ---------------- xw[t][b][:] = x_t @ W_td3^T + td ---------------------------
__global__ __launch_bounds__(256) void k_xw(
    const float* __restrict__ word_embs, const float* __restrict__ td3t,
    const float* __restrict__ td, float* __restrict__ xw) {
  __shared__ float xl[4 * 300];
  __shared__ float tdl[512];
  int t = blockIdx.y, b0 = blockIdx.x * 4, tid = threadIdx.x;
  #pragma unroll
  for (int r = 0; r < 4; ++r) {
    const float* xs = word_embs + (size_t)(b0 + r) * (kT * kE) + (size_t)t * kE;
    for (int e = tid; e < kE; e += 256) xl[r * kE + e] = xs[e];
  }
  for (int i = tid; i < 512; i += 256) tdl[i] = td[(size_t)b0 * kC + i];
  __syncthreads();
  #pragma unroll
  for (int q = 0; q < 2; ++q) {
    int idx = tid + q * 256;
    int r = idx >> 7, c = idx & 127;
    float acc = tdl[idx];
    const float* xr = xl + r * kE;
    const float* w3 = td3t + c;
    for (int e = 0; e < kE; ++e) acc = fmaf(xr[e], w3[(size_t)e * 128], acc);
    xw[((size_t)t * kB + b0 + r) * kC + c] = acc;
  }
}

// ---------------- LDS-staged split-bf16 MFMA 128x128 tile (3-term) -----------
// 256 threads. Stages 128x32 bf16 tiles; 16B slot XOR-swizzled by (row>>1)&3
// so quarter-wave ds_read_b128 spreads over 8 bank-starts (2-way max = free).
__device__ __forceinline__ void mm_tile_lds(
    const unsigned short* __restrict__ Ah, const unsigned short* __restrict__ Al,
    const unsigned short* __restrict__ Bh, const unsigned short* __restrict__ Bl,
    int m0, int n0, int K, int kbeg, int kend, int nMax, f32x4 acc[4][4],
    unsigned short* sAh, unsigned short* sAl,
    unsigned short* sBh, unsigned short* sBl) {
  int tid = threadIdx.x;
  int lane = tid & 63, wid = tid >> 6;
  int wm = (wid >> 1) * 64, wn = (wid & 1) * 64;
  int r16 = lane & 15, kq = lane >> 4;
  int rA = tid >> 2;
  int swSlot = (((tid & 3) ^ ((rA >> 1) & 3)) * 8);   // write-side swizzle
  int cA = (tid & 3) * 8;                             // global k-chunk
  int swr = (kq ^ ((r16 >> 1) & 3)) * 8;              // read-side swizzle
  int brow0 = n0 + rA;       if (brow0 > nMax) brow0 = nMax;
  int brow1 = n0 + rA + 64;  if (brow1 > nMax) brow1 = nMax;
  for (int k0 = kbeg; k0 < kend; k0 += 32) {
    uint4 va0 = *(const uint4*)(Ah + (size_t)(m0 + rA) * K + k0 + cA);
    uint4 va1 = *(const uint4*)(Ah + (size_t)(m0 + rA + 64) * K + k0 + cA);
    uint4 vb0 = *(const uint4*)(Al + (size_t)(m0 + rA) * K + k0 + cA);
    uint4 vb1 = *(const uint4*)(Al + (size_t)(m0 + rA + 64) * K + k0 + cA);
    uint4 vc0 = *(const uint4*)(Bh + (size_t)brow0 * K + k0 + cA);
    uint4 vc1 = *(const uint4*)(Bh + (size_t)brow1 * K + k0 + cA);
    uint4 vd0 = *(const uint4*)(Bl + (size_t)brow0 * K + k0 + cA);
    uint4 vd1 = *(const uint4*)(Bl + (size_t)brow1 * K + k0 + cA);
    __syncthreads();   // previous chunk's reads complete
    *(uint4*)&sAh[rA * 32 + swSlot] = va0;
    *(uint4*)&sAh[(rA + 64) * 32 + swSlot] = va1;   // (rA+64)>>1 & 3 == (rA>>1)&3
    *(uint4*)&sAl[rA * 32 + swSlot] = vb0;
    *(uint4*)&sAl[(rA + 64) * 32 + swSlot] = vb1;
    *(uint4*)&sBh[rA * 32 + swSlot] = vc0;
    *(uint4*)&sBh[(rA + 64) * 32 + swSlot] = vc1;
    *(uint4*)&sBl[rA * 32 + swSlot] = vd0;
    *(uint4*)&sBl[(rA + 64) * 32 + swSlot] = vd1;
    __syncthreads();
    bf16x8 ah[4], al[4], bh[4], bl[4];
    #pragma unroll
    for (int i = 0; i < 4; ++i) {
      int ar = (wm + i * 16 + r16) * 32 + swr;
      int br = (wn + i * 16 + r16) * 32 + swr;
      ah[i] = *(const bf16x8*)&sAh[ar];
      al[i] = *(const bf16x8*)&sAl[ar];
      bh[i] = *(const bf16x8*)&sBh[br];
      bl[i] = *(const bf16x8*)&sBl[br];
    }
    #pragma unroll
    for (int i = 0; i < 4; ++i)
      #pragma unroll
      for (int j = 0; j < 4; ++j) {
        acc[i][j] = __builtin_amdgcn_mfma_f32_16x16x32_bf16(ah[i], bh[j], acc[i][j], 0, 0, 0);
        acc[i][j] = __builtin_amdgcn_mfma_f32_16x16x32_bf16(ah[i], bl[j], acc[i][j], 0, 0, 0);
        acc[i][j] = __builtin_amdgcn_mfma_f32_16x16x32_bf16(al[i], bh[j], acc[i][j], 0, 0, 0);
      }
  }
}

// ---------------- feat_proj = c_feats @ W_feat^T -> bf16 (MFMA) --------------
__global__ __launch_bounds__(256) void k_featproj(
    const float* __restrict__ A, const unsigned short* __restrict__ Wh,
    const unsigned short* __restrict__ Wl, unsigned short* __restrict__ out) {
  int lane = threadIdx.x & 63, wid = threadIdx.x >> 6;
  int wm = (wid >> 1) * 64, wn = (wid & 1) * 64;
  int r16 = lane & 15, kq = lane >> 4;
  int m0 = blockIdx.x * 128, n0 = blockIdx.y * 128;
  f32x4 acc[4][4];
  #pragma unroll
  for (int i = 0; i < 4; ++i)
    #pragma unroll
    for (int j = 0; j < 4; ++j) acc[i][j] = (f32x4){0.f, 0.f, 0.f, 0.f};
  for (int k0 = 0; k0 < kC; k0 += 32) {
    int kk = k0 + kq * 8;
    bf16x8 ah[4], al[4], bh[4], bl[4];
    #pragma unroll
    for (int i = 0; i < 4; ++i) {
      const float* pa = A + (size_t)(m0 + wm + i * 16 + r16) * kC + kk;
      float4 v0 = *(const float4*)pa;
      float4 v1 = *(const float4*)(pa + 4);
      float vv[8] = {v0.x, v0.y, v0.z, v0.w, v1.x, v1.y, v1.z, v1.w};
      union { unsigned short s[8]; bf16x8 v; } uh, ul;
      #pragma unroll
      for (int q = 0; q < 8; ++q) {
        unsigned short hb = f2bf(vv[q]);
        uh.s[q] = hb;
        ul.s[q] = f2bf(vv[q] - bf2f(hb));
      }
      ah[i] = uh.v; al[i] = ul.v;
      const unsigned short* pb = Wh + (size_t)(n0 + wn + i * 16 + r16) * kC + kk;
      const unsigned short* pl = Wl + (size_t)(n0 + wn + i * 16 + r16) * kC + kk;
      union { uint4 u; bf16x8 v; } xb, xl2;
      xb.u = *(const uint4*)pb; xl2.u = *(const uint4*)pl;
      bh[i] = xb.v; bl[i] = xl2.v;
    }
    #pragma unroll
    for (int i = 0; i < 4; ++i)
      #pragma unroll
      for (int j = 0; j < 4; ++j) {
        acc[i][j] = __builtin_amdgcn_mfma_f32_16x16x32_bf16(ah[i], bh[j], acc[i][j], 0, 0, 0);
        acc[i][j] = __builtin_amdgcn_mfma_f32_16x16x32_bf16(ah[i], bl[j], acc[i][j], 0, 0, 0);
        acc[i][j] = __builtin_amdgcn_mfma_f32_16x16x32_bf16(al[i], bh[j], acc[i][j], 0, 0, 0);
      }
  }
  #pragma unroll
  for (int i = 0; i < 4; ++i)
    #pragma unroll
    for (int j = 0; j < 4; ++j)
      #pragma unroll
      for (int r = 0; r < 4; ++r) {
        int m = m0 + wm + i * 16 + kq * 4 + r;
        int n = n0 + wn + j * 16 + r16;
        out[(size_t)m * kH + n] = f2bf(acc[i][j][r]);
      }
}

// ---------------- per-step kernel 1 (k_pre): gh MFMA || s-chain+gx1 GEMV -----
// Blocks 0..95:  gh1/gh2 split-bf16 MFMA, K-split x2 (partials, bias in half 0)
// Blocks 96..159: s = relu(tanh(xw[t]+h2@W_td1^T)@W_td^T); gx1 = s@W1_ih^T+b.
//                 4 batch rows per block, bf16 weights, fp32 activations.
__global__ __launch_bounds__(256) void k_pre(
    const unsigned short* __restrict__ h1h, const unsigned short* __restrict__ h1l,
    const unsigned short* __restrict__ h2h, const unsigned short* __restrict__ h2l,
    const unsigned short* __restrict__ w1hh_h, const unsigned short* __restrict__ w1hh_l,
    const unsigned short* __restrict__ w2hh_h, const unsigned short* __restrict__ w2hh_l,
    const float* __restrict__ b1_hh, const float* __restrict__ b2_hh,
    float* __restrict__ gh1, float* __restrict__ gh2,
    const float* __restrict__ h2, const float* __restrict__ xw, int t,
    const unsigned short* __restrict__ td1bt, const unsigned short* __restrict__ tdbt,
    const unsigned short* __restrict__ iht1b, const float* __restrict__ b1_ih,
    float* __restrict__ gx1) {
  __shared__ __align__(16) unsigned char smemraw[32768];
  int blk = blockIdx.x, tid = threadIdx.x;
  if (blk < 96) {
    unsigned short* sAh = (unsigned short*)smemraw;
    unsigned short* sAl = sAh + 4096;
    unsigned short* sBh = sAl + 4096;
    unsigned short* sBl = sBh + 4096;
    int half = blk & 1, g = blk >> 1;   // g 0..47
    const unsigned short *Ah, *Al, *Wh, *Wl; const float* bias; float* out;
    if (g < 24) { Ah = h1h; Al = h1l; Wh = w1hh_h; Wl = w1hh_l;
                  bias = b1_hh; out = gh1; }
    else { g -= 24; Ah = h2h; Al = h2l; Wh = w2hh_h; Wl = w2hh_l;
           bias = b2_hh; out = gh2; }
    out += (size_t)half * (kB * kG);
    int m0 = (g / 12) * 128, n0 = (g % 12) * 128;
    f32x4 acc[4][4];
    #pragma unroll
    for (int i = 0; i < 4; ++i)
      #pragma unroll
      for (int j = 0; j < 4; ++j) acc[i][j] = (f32x4){0.f, 0.f, 0.f, 0.f};
    mm_tile_lds(Ah, Al, Wh, Wl, m0, n0, kH, half * 256, half * 256 + 256,
                kG - 1, acc, sAh, sAl, sBh, sBl);
    int lane = tid & 63, wid = tid >> 6;
    int wm = (wid >> 1) * 64, wn = (wid & 1) * 64;
    int r16 = lane & 15, kq = lane >> 4;
    #pragma unroll
    for (int i = 0; i < 4; ++i)
      #pragma unroll
      for (int j = 0; j < 4; ++j)
        #pragma unroll
        for (int r = 0; r < 4; ++r) {
          int m = m0 + wm + i * 16 + kq * 4 + r;
          int n = n0 + wn + j * 16 + r16;
          float v = acc[i][j][r];
          if (half == 0) v += bias[n];
          out[(size_t)m * kG + n] = v;
        }
  } else {
    // ---- s-chain + gx1 for 4 batch rows ----
    float* h2loc = (float*)smemraw;        // 4*512
    float* part  = h2loc + 2048;           // 8*512
    float* s1    = part + 4096;            // 4*128
    float* s2    = s1 + 512;               // 4*128
    int b0 = (blk - 96) * 4;
    for (int i = tid; i < 512; i += 256)
      *(float4*)&h2loc[i * 4] = *(const float4*)(h2 + (size_t)b0 * kH + i * 4);
    __syncthreads();
    // s1 = tanh(xw + h2 @ W_td1^T): 32 cg(4c) x 8 kg(64k)
    {
      int cg = tid & 31, kg = tid >> 5;
      float acc[4][4] = {};
      for (int k = 0; k < 64; ++k) {
        int gk = kg * 64 + k;
        union { uint2 u; unsigned short s[4]; } wu;
        wu.u = *(const uint2*)(td1bt + (size_t)gk * kC + cg * 4);
        #pragma unroll
        for (int r = 0; r < 4; ++r) {
          float h = h2loc[r * 512 + gk];
          acc[r][0] = fmaf(h, bf2f(wu.s[0]), acc[r][0]);
          acc[r][1] = fmaf(h, bf2f(wu.s[1]), acc[r][1]);
          acc[r][2] = fmaf(h, bf2f(wu.s[2]), acc[r][2]);
          acc[r][3] = fmaf(h, bf2f(wu.s[3]), acc[r][3]);
        }
      }
      #pragma unroll
      for (int r = 0; r < 4; ++r)
        #pragma unroll
        for (int j = 0; j < 4; ++j)
          part[kg * 512 + r * 128 + cg * 4 + j] = acc[r][j];
    }
    __syncthreads();
    for (int idx = tid; idx < 512; idx += 256) {
      int r = idx >> 7, c = idx & 127;
      float s = xw[((size_t)t * kB + b0 + r) * kC + c];
      #pragma unroll
      for (int g = 0; g < 8; ++g) s += part[g * 512 + idx];
      s1[idx] = ftanh(s);
    }
    __syncthreads();
    // s2 = relu(s1 @ W_td^T): 32 cg(4c) x 8 kg(16k)
    {
      int cg = tid & 31, kg = tid >> 5;
      float acc[4][4] = {};
      for (int k = 0; k < 16; ++k) {
        int gk = kg * 16 + k;
        union { uint2 u; unsigned short s[4]; } wu;
        wu.u = *(const uint2*)(tdbt + (size_t)gk * kC + cg * 4);
        #pragma unroll
        for (int r = 0; r < 4; ++r) {
          float h = s1[r * 128 + gk];
          acc[r][0] = fmaf(h, bf2f(wu.s[0]), acc[r][0]);
          acc[r][1] = fmaf(h, bf2f(wu.s[1]), acc[r][1]);
          acc[r][2] = fmaf(h, bf2f(wu.s[2]), acc[r][2]);
          acc[r][3] = fmaf(h, bf2f(wu.s[3]), acc[r][3]);
        }
      }
      #pragma unroll
      for (int r = 0; r < 4; ++r)
        #pragma unroll
        for (int j = 0; j < 4; ++j)
          part[kg * 512 + r * 128 + cg * 4 + j] = acc[r][j];
    }
    __syncthreads();
    for (int idx = tid; idx < 512; idx += 256) {
      float s = 0.f;
      #pragma unroll
      for (int g = 0; g < 8; ++g) s += part[g * 512 + idx];
      s2[idx] = fmaxf(s, 0.f);
    }
    __syncthreads();
    // gx1 = s2 @ W1_ih^T + b1_ih: groups of 4 cols, full K=128
    for (int g = tid; g < 384; g += 256) {
      int c0 = g * 4;
      float acc[4][4] = {};
      for (int k = 0; k < kC; ++k) {
        union { uint2 u; unsigned short s[4]; } wu;
        wu.u = *(const uint2*)(iht1b + (size_t)k * kG + c0);
        #pragma unroll
        for (int r = 0; r < 4; ++r) {
          float h = s2[r * 128 + k];
          acc[r][0] = fmaf(h, bf2f(wu.s[0]), acc[r][0]);
          acc[r][1] = fmaf(h, bf2f(wu.s[1]), acc[r][1]);
          acc[r][2] = fmaf(h, bf2f(wu.s[2]), acc[r][2]);
          acc[r][3] = fmaf(h, bf2f(wu.s[3]), acc[r][3]);
        }
      }
      float4 bv = *(const float4*)(b1_ih + c0);
      #pragma unroll
      for (int r = 0; r < 4; ++r) {
        float4 o = make_float4(acc[r][0] + bv.x, acc[r][1] + bv.y,
                               acc[r][2] + bv.z, acc[r][3] + bv.w);
        *(float4*)(gx1 + (size_t)(b0 + r) * kG + c0) = o;
      }
    }
  }
}

// ---------------- per-step kernel 2: one batch row per block, 1024 threads ---
__global__ __launch_bounds__(1024, 4) void k_step2(
    const float* __restrict__ gx1, const float* __restrict__ gh1,
    const float* __restrict__ gh2,
    float* __restrict__ h1, float* __restrict__ h2,
    unsigned short* __restrict__ h1h, unsigned short* __restrict__ h1l,
    unsigned short* __restrict__ h2h, unsigned short* __restrict__ h2l,
    const unsigned short* __restrict__ whdbT, const float* __restrict__ W_att,
    const unsigned short* __restrict__ fp, const float* __restrict__ c_feats,
    const unsigned short* __restrict__ l1bt, const unsigned short* __restrict__ l2bt,
    const unsigned short* __restrict__ lbt, const unsigned short* __restrict__ iht2b,
    const float* __restrict__ b2_ih,
    unsigned short* __restrict__ h2all_h, unsigned short* __restrict__ h2all_l,
    float* __restrict__ mask_ws, int t) {
  __shared__ float partbuf[8192];     // 32 KB, reused across phases
  __shared__ float h1p[512];
  __shared__ float hqs[512];
  __shared__ float scs[256];
  __shared__ float red[16];
  __shared__ float red2[16];
  __shared__ float attl[128];
  __shared__ float lt1[128];
  __shared__ float llv[128];
  __shared__ float gx2l[1536];
  const int b = blockIdx.x;
  const int tid = threadIdx.x;
  const int lane = tid & 63, wv = tid >> 6;   // 16 waves
  const size_t GPART = (size_t)kB * kG;       // gh k-split partial offset

  // ---- A: GRU1 combine -> h1' ----
  if (tid < 512) {
    int c = tid;
    float gr = gx1[(size_t)b * kG + c];
    float gz = gx1[(size_t)b * kG + 512 + c];
    float gn = gx1[(size_t)b * kG + 1024 + c];
    float hr = gh1[(size_t)b * kG + c] + gh1[GPART + (size_t)b * kG + c];
    float hz = gh1[(size_t)b * kG + 512 + c] + gh1[GPART + (size_t)b * kG + 512 + c];
    float hnv = gh1[(size_t)b * kG + 1024 + c] + gh1[GPART + (size_t)b * kG + 1024 + c];
    float rr = fsigm(gr + hr);
    float zz = fsigm(gz + hz);
    float nn = ftanh(gn + rr * hnv);
    float ho = h1[(size_t)b * kH + c];
    float hn = (1.f - zz) * nn + zz * ho;
    h1[(size_t)b * kH + c] = hn;
    h1p[c] = hn;
    unsigned short hb = f2bf(hn);
    h1h[(size_t)b * kH + c] = hb;
    h1l[(size_t)b * kH + c] = f2bf(hn - bf2f(hb));
  }
  __syncthreads();

  // ---- B: hq = h1' @ W_hidd^T. 64 col-groups(8) x 16 k-groups(32) ----
  {
    int cg = tid & 63, kg = tid >> 6;   // kg 0..15
    int c0 = cg * 8;
    const unsigned short* w = whdbT + (size_t)(kg * 32) * kH + c0;
    float acc[8] = {};
    #pragma unroll 4
    for (int k = 0; k < 32; ++k) {
      union { uint4 u; unsigned short s[8]; } wu;
      wu.u = *(const uint4*)(w + (size_t)k * kH);
      float h = h1p[kg * 32 + k];
      #pragma unroll
      for (int j = 0; j < 8; ++j) acc[j] = fmaf(h, bf2f(wu.s[j]), acc[j]);
    }
    float* pp = &partbuf[kg * 512 + c0];
    #pragma unroll
    for (int j = 0; j < 8; ++j) pp[j] = acc[j];
  }
  __syncthreads();
  if (tid < 512) {
    float s = 0.f;
    #pragma unroll
    for (int g = 0; g < 16; ++g) s += partbuf[g * 512 + tid];
    hqs[tid] = s;
  }
  __syncthreads();

  // ---- C: attention scores (exp-tanh), 16 waves x 16 proposals ----
  {
    float hq8[8], aw[8];
    #pragma unroll
    for (int j = 0; j < 8; ++j) hq8[j] = hqs[lane * 8 + j];
    {
      float4 a0 = *(const float4*)(W_att + lane * 8);
      float4 a1 = *(const float4*)(W_att + lane * 8 + 4);
      aw[0] = a0.x; aw[1] = a0.y; aw[2] = a0.z; aw[3] = a0.w;
      aw[4] = a1.x; aw[5] = a1.y; aw[6] = a1.z; aw[7] = a1.w;
    }
    const unsigned short* fpb = fp + (size_t)b * kP * kH;
    int p0 = wv * 16;
    uint4 rv = *(const uint4*)(fpb + (size_t)p0 * kH + lane * 8);
    for (int p = p0; p < p0 + 16; ++p) {
      union { uint4 v; unsigned short s[8]; } u; u.v = rv;
      if (p + 1 < p0 + 16)
        rv = *(const uint4*)(fpb + (size_t)(p + 1) * kH + lane * 8);
      float sc = 0.f;
      #pragma unroll
      for (int j = 0; j < 8; ++j) {
        float f = __uint_as_float((unsigned)u.s[j] << 16);
        sc += aw[j] * ftanh(f + hq8[j]);
      }
      #pragma unroll
      for (int m = 32; m; m >>= 1) sc += __shfl_xor(sc, m, 64);
      if (lane == 0) scs[p] = sc;
    }
  }
  __syncthreads();

  // ---- D: softmax over 256 proposals ----
  {
    float sv = (tid < 256) ? scs[tid] : -1e30f;
    float mx = sv;
    #pragma unroll
    for (int m = 32; m; m >>= 1) mx = fmaxf(mx, __shfl_xor(mx, m, 64));
    if (lane == 0) red[wv] = mx;
    __syncthreads();
    float bm = red[0];
    #pragma unroll
    for (int i = 1; i < 16; ++i) bm = fmaxf(bm, red[i]);
    float ev = (tid < 256) ? fexp2((sv - bm) * 1.4426950408889634f) : 0.f;
    float sm = ev;
    #pragma unroll
    for (int m = 32; m; m >>= 1) sm += __shfl_xor(sm, m, 64);
    if (lane == 0) red2[wv] = sm;
    __syncthreads();
    float tot = 0.f;
    #pragma unroll
    for (int i = 0; i < 16; ++i) tot += red2[i];
    if (tid < 256) {
      float mk = ev * frcp(tot);
      scs[tid] = mk;
      mask_ws[(size_t)t * (kB * kP) + (size_t)b * kP + tid] = mk;
    }
  }
  __syncthreads();

  // ---- E: attended = mask @ c_feats, 8 proposal-groups x 32 ----
  {
    int c = tid & 127, q = tid >> 7;
    const float* cf = c_feats + ((size_t)b * kP + q * 32) * kC + c;
    const float* ms = scs + q * 32;
    float acc = 0.f;
    for (int p = 0; p < 32; ++p) acc = fmaf(ms[p], cf[(size_t)p * kC], acc);
    partbuf[q * 128 + c] = acc;
  }
  __syncthreads();
  if (tid < 128) {
    float s = 0.f;
    #pragma unroll
    for (int q = 0; q < 8; ++q) s += partbuf[q * 128 + tid];
    attl[tid] = s;
  }
  __syncthreads();

  // ---- F: lt1 = tanh(att@W_l1^T + h1'@W_l2^T) ----
  {
    if (tid < 512) {
      int cg = tid & 15, kg = tid >> 4;
      int c0 = cg * 8;
      const unsigned short* w = l2bt + (size_t)(kg * 16) * kC + c0;
      float acc[8] = {};
      for (int k = 0; k < 16; ++k) {
        union { uint4 u; unsigned short s[8]; } wu;
        wu.u = *(const uint4*)(w + (size_t)k * kC);
        float h = h1p[kg * 16 + k];
        #pragma unroll
        for (int j = 0; j < 8; ++j) acc[j] = fmaf(h, bf2f(wu.s[j]), acc[j]);
      }
      float* pp = &partbuf[kg * 128 + c0];
      #pragma unroll
      for (int j = 0; j < 8; ++j) pp[j] = acc[j];
    } else if (tid < 768) {
      int tt = tid - 512;
      int cg = tt & 15, kg = tt >> 4;
      int c0 = cg * 8;
      const unsigned short* w = l1bt + (size_t)(kg * 8) * kC + c0;
      float acc[8] = {};
      for (int k = 0; k < 8; ++k) {
        union { uint4 u; unsigned short s[8]; } wu;
        wu.u = *(const uint4*)(w + (size_t)k * kC);
        float a = attl[kg * 8 + k];
        #pragma unroll
        for (int j = 0; j < 8; ++j) acc[j] = fmaf(a, bf2f(wu.s[j]), acc[j]);
      }
      float* pp = &partbuf[4096 + kg * 128 + c0];
      #pragma unroll
      for (int j = 0; j < 8; ++j) pp[j] = acc[j];
    }
  }
  __syncthreads();
  if (tid < 128) {
    float s = 0.f;
    #pragma unroll
    for (int g = 0; g < 32; ++g) s += partbuf[g * 128 + tid];
    #pragma unroll
    for (int g = 0; g < 16; ++g) s += partbuf[4096 + g * 128 + tid];
    lt1[tid] = ftanh(s);
  }
  __syncthreads();

  // ---- G: llv = relu(lt1 @ W_l^T), 16 cg x 16 kg (k=8) ----
  if (tid < 256) {
    int cg = tid & 15, kg = tid >> 4;
    int c0 = cg * 8;
    const unsigned short* w = lbt + (size_t)(kg * 8) * kC + c0;
    float acc[8] = {};
    for (int k = 0; k < 8; ++k) {
      union { uint4 u; unsigned short s[8]; } wu;
      wu.u = *(const uint4*)(w + (size_t)k * kC);
      float l = lt1[kg * 8 + k];
      #pragma unroll
      for (int j = 0; j < 8; ++j) acc[j] = fmaf(l, bf2f(wu.s[j]), acc[j]);
    }
    float* pp = &partbuf[kg * 128 + c0];
    #pragma unroll
    for (int j = 0; j < 8; ++j) pp[j] = acc[j];
  }
  __syncthreads();
  if (tid < 128) {
    float s = 0.f;
    #pragma unroll
    for (int g = 0; g < 16; ++g) s += partbuf[g * 128 + tid];
    llv[tid] = fmaxf(s, 0.f);
  }
  __syncthreads();

  // ---- H: gx2 = llv @ W2_ih^T + b2. 192 cg(8) x 4 kg(32) ----
  if (tid < 768) {
    int cg = tid % 192, kg = tid / 192;
    int c0 = cg * 8;
    const unsigned short* w = iht2b + (size_t)(kg * 32) * kG + c0;
    float acc[8] = {};
    #pragma unroll 4
    for (int k = 0; k < 32; ++k) {
      union { uint4 u; unsigned short s[8]; } wu;
      wu.u = *(const uint4*)(w + (size_t)k * kG);
      float l = llv[kg * 32 + k];
      #pragma unroll
      for (int j = 0; j < 8; ++j) acc[j] = fmaf(l, bf2f(wu.s[j]), acc[j]);
    }
    float* pp = &partbuf[kg * 1536 + c0];
    #pragma unroll
    for (int j = 0; j < 8; ++j) pp[j] = acc[j];
  }
  __syncthreads();
  for (int c = tid; c < kG; c += 1024) {
    float s = b2_ih[c];
    #pragma unroll
    for (int g = 0; g < 4; ++g) s += partbuf[g * 1536 + c];
    gx2l[c] = s;
  }
  __syncthreads();
  if (tid < 512) {
    int c = tid;
    float ghr = gh2[(size_t)b * kG + c] + gh2[GPART + (size_t)b * kG + c];
    float ghz = gh2[(size_t)b * kG + 512 + c] + gh2[GPART + (size_t)b * kG + 512 + c];
    float ghn = gh2[(size_t)b * kG + 1024 + c] + gh2[GPART + (size_t)b * kG + 1024 + c];
    float rr = fsigm(gx2l[c] + ghr);
    float zz = fsigm(gx2l[512 + c] + ghz);
    float nn = ftanh(gx2l[1024 + c] + rr * ghn);
    float ho = h2[(size_t)b * kH + c];
    float hn = (1.f - zz) * nn + zz * ho;
    h2[(size_t)b * kH + c] = hn;
    unsigned short hb = f2bf(hn);
    unsigned short lb = f2bf(hn - bf2f(hb));
    h2h[(size_t)b * kH + c] = hb;
    h2l[(size_t)b * kH + c] = lb;
    size_t o = ((size_t)t * kB + b) * kH + c;
    h2all_h[o] = hb;
    h2all_l[o] = lb;
  }
}

// ---------------- mask transpose via LDS: [t][b][p] -> out[b][p][t] ----------
__global__ __launch_bounds__(256) void k_atrans(
    const float* __restrict__ mws, float* __restrict__ attn_out) {
  __shared__ float tile[256][33];
  int pair0 = blockIdx.x * 256;     // 256 blocks cover 65536 (b,p) pairs
  int tid = threadIdx.x;
  #pragma unroll
  for (int t = 0; t < kNS; ++t)
    tile[tid][t] = mws[(size_t)t * (kB * kP) + pair0 + tid];
  __syncthreads();
  float* outb = attn_out + (size_t)pair0 * kNS;
  #pragma unroll
  for (int i = 0; i < kNS; ++i) {
    int g = i * 256 + tid;           // 0..7935 contiguous output floats
    int pr = g / 31, tt = g - pr * 31;
    outb[g] = tile[pr][tt];
  }
}

// ---------------- classifier: lang = h2_all @ W_cls^T + b_cls (MFMA, LDS) ----
__global__ __launch_bounds__(256) void k_cls(
    const unsigned short* __restrict__ Ah, const unsigned short* __restrict__ Al,
    const unsigned short* __restrict__ Wh, const unsigned short* __restrict__ Wl,
    const float* __restrict__ bc, float* __restrict__ out) {
  __shared__ __align__(16) unsigned short sAh[4096], sAl[4096], sBh[4096], sBl[4096];
  int m0 = blockIdx.x * 128, n0 = blockIdx.y * 128;
  f32x4 acc[4][4];
  #pragma unroll
  for (int i = 0; i < 4; ++i)
    #pragma unroll
    for (int j = 0; j < 4; ++j) acc[i][j] = (f32x4){0.f, 0.f, 0.f, 0.f};
  mm_tile_lds(Ah, Al, Wh, Wl, m0, n0, kH, 0, kH, kV - 1, acc,
              sAh, sAl, sBh, sBl);
  int lane = threadIdx.x & 63, wid = threadIdx.x >> 6;
  int wm = (wid >> 1) * 64, wn = (wid & 1) * 64;
  int r16 = lane & 15, kq = lane >> 4;
  #pragma unroll
  for (int i = 0; i < 4; ++i)
    #pragma unroll
    for (int j = 0; j < 4; ++j)
      #pragma unroll
      for (int r = 0; r < 4; ++r) {
        int m = m0 + wm + i * 16 + kq * 4 + r;
        int n = n0 + wn + j * 16 + r16;
        if (n < kV) {
          int tt = m >> 8, b = m & 255;
          out[(size_t)b * (kNS * kV) + (size_t)tt * kV + n] = acc[i][j][r] + bc[n];
        }
      }
}

}  // namespace

extern "C" void kernel_launch(void* const* d_in, const int* in_sizes, int n_in,
                              void* d_out, int out_size, void* d_ws,
                              size_t ws_size, hipStream_t stream) {
  (void)in_sizes; (void)n_in; (void)out_size; (void)ws_size;
  const float* word_embs = (const float*)d_in[0];
  const float* t_feat    = (const float*)d_in[1];
  const float* c_feats   = (const float*)d_in[2];
  const float* W_td1 = (const float*)d_in[4];
  const float* W_td2 = (const float*)d_in[5];
  const float* W_td3 = (const float*)d_in[6];
  const float* W_td  = (const float*)d_in[7];
  const float* W1_ih = (const float*)d_in[8];
  const float* W1_hh = (const float*)d_in[9];
  const float* b1_ih = (const float*)d_in[10];
  const float* b1_hh = (const float*)d_in[11];
  const float* W_feat = (const float*)d_in[12];
  const float* W_hidd = (const float*)d_in[13];
  const float* W_att  = (const float*)d_in[14];
  const float* W_l1 = (const float*)d_in[15];
  const float* W_l2 = (const float*)d_in[16];
  const float* W_l  = (const float*)d_in[17];
  const float* W2_ih = (const float*)d_in[18];
  const float* W2_hh = (const float*)d_in[19];
  const float* b2_ih = (const float*)d_in[20];
  const float* b2_hh = (const float*)d_in[21];
  const float* W_cls = (const float*)d_in[22];
  const float* b_cls = (const float*)d_in[23];

  float* lang = (float*)d_out;
  float* attn_out = lang + (size_t)kB * kNS * kV;
  // feat_proj (bf16, 64MB) lives in the lang_cap region of d_out — dead by
  // the time k_cls (the only writer of lang_cap) runs.
  unsigned short* fp = (unsigned short*)d_out;

  float* p = (float*)d_ws;
  float* h1 = p;      p += kB * kH;
  float* h2 = p;      p += kB * kH;
  float* td = p;      p += kB * kC;
  float* gx1 = p;     p += (size_t)kB * kG;
  float* gh1 = p;     p += (size_t)2 * kB * kG;   // 2 K-split partials
  float* gh2 = p;     p += (size_t)2 * kB * kG;
  float* mask_ws = p; p += (size_t)kNS * kB * kP;
  float* xw = p;      p += (size_t)kNS * kB * kC;
  float* td3t = p;    p += kE * 128;
  float* td1t = p;    p += kH * 128;
  float* tdt  = p;    p += 128 * 128;
  float* l1t  = p;    p += 128 * 128;
  float* l2t  = p;    p += kH * 128;
  float* lt   = p;    p += 128 * 128;
  float* iht1 = p;    p += 128 * kG;
  float* iht2 = p;    p += 128 * kG;
  float* whd_t = p;   p += kH * kH;

  unsigned short* u = (unsigned short*)p;
  unsigned short* h1h = u;     u += kB * kH;
  unsigned short* h1l = u;     u += kB * kH;
  unsigned short* h2h = u;     u += kB * kH;
  unsigned short* h2l = u;     u += kB * kH;
  unsigned short* w1hh_h = u;  u += (size_t)kG * kH;
  unsigned short* w1hh_l = u;  u += (size_t)kG * kH;
  unsigned short* w2hh_h = u;  u += (size_t)kG * kH;
  unsigned short* w2hh_l = u;  u += (size_t)kG * kH;
  unsigned short* wc_h = u;    u += (size_t)kV * kH;
  unsigned short* wc_l = u;    u += (size_t)kV * kH;
  unsigned short* wf_h = u;    u += (size_t)kH * kC;
  unsigned short* wf_l = u;    u += (size_t)kH * kC;
  unsigned short* h2all_h = u; u += (size_t)kNS * kB * kH;
  unsigned short* h2all_l = u; u += (size_t)kNS * kB * kH;
  unsigned short* l1bt = u;    u += kC * kC;
  unsigned short* l2bt = u;    u += (size_t)kH * kC;
  unsigned short* lbt = u;     u += kC * kC;
  unsigned short* iht2b = u;   u += (size_t)kC * kG;
  unsigned short* whdbT = u;   u += (size_t)kH * kH;
  unsigned short* td1bt = u;   u += (size_t)kH * kC;
  unsigned short* tdbt = u;    u += kC * kC;
  unsigned short* iht1b = u;   u += (size_t)kC * kG;

  k_transpose<<<dim3(64, 9), 256, 0, stream>>>(
      W_td3, W_td1, W_td, W_l1, W_l2, W_l, W1_ih, W2_ih, W_hidd,
      td3t, td1t, tdt, l1t, l2t, lt, iht1, iht2, whd_t);
  k_tobf16<<<dim3(96, 8), 256, 0, stream>>>(
      l1t, l2t, lt, iht2, whd_t, td1t, tdt, iht1,
      l1bt, l2bt, lbt, iht2b, whdbT, td1bt, tdbt, iht1b);
  k_split<<<dim3(256, 4), 256, 0, stream>>>(
      W1_hh, W2_hh, W_cls, W_feat,
      w1hh_h, w1hh_l, w2hh_h, w2hh_l, wc_h, wc_l, wf_h, wf_l);
  k_init<<<128, 256, 0, stream>>>(t_feat, W_td2, td, h1, h2,
                                  h1h, h1l, h2h, h2l);
  k_featproj<<<dim3(512, 4), 256, 0, stream>>>(c_feats, wf_h, wf_l, fp);
  k_xw<<<dim3(64, kNS), 256, 0, stream>>>(word_embs, td3t, td, xw);

  for (int t = 0; t < kNS; ++t) {
    k_pre<<<160, 256, 0, stream>>>(h1h, h1l, h2h, h2l,
                                   w1hh_h, w1hh_l, w2hh_h, w2hh_l,
                                   b1_hh, b2_hh, gh1, gh2,
                                   h2, xw, t, td1bt, tdbt, iht1b, b1_ih, gx1);
    k_step2<<<256, 1024, 0, stream>>>(gx1, gh1, gh2, h1, h2,
                                      h1h, h1l, h2h, h2l, whdbT, W_att, fp,
                                      c_feats, l1bt, l2bt, lbt, iht2b, b2_ih,
                                      h2all_h, h2all_l, mask_ws, t);
  }
  k_atrans<<<256, 256, 0, stream>>>(mask_ws, attn_out);
  k_cls<<<dim3(62, 27), 256, 0, stream>>>(h2all_h, h2all_l, wc_h, wc_l,
                                          b_cls, lang);
}

// Round 11
// 2205.697 us; speedup vs baseline: 1.1149x; 1.1149x over previous
//
#include <hip/hip_runtime.h>
#include <hip/hip_bf16.h>

namespace {

constexpr int kB  = 256;   // batch
constexpr int kP  = 256;   // proposals
constexpr int kT  = 32;    // words
constexpr int kNS = 31;    // steps = T-1
constexpr int kV  = 3433;  // vocab
constexpr int kH  = 512;   // hidden
constexpr int kE  = 300;   // embed
constexpr int kC  = 128;   // feat dim
constexpr int kG  = 1536;  // 3H

typedef __bf16 bf16x8 __attribute__((ext_vector_type(8)));
typedef float f32x4 __attribute__((ext_vector_type(4)));

__device__ __forceinline__ float fexp2(float x) {
  float r; asm("v_exp_f32 %0, %1" : "=v"(r) : "v"(x)); return r;
}
__device__ __forceinline__ float frcp(float x) {
  float r; asm("v_rcp_f32 %0, %1" : "=v"(r) : "v"(x)); return r;
}
__device__ __forceinline__ float ftanh(float x) {
  float e = fexp2(x * 2.8853900817779268f);   // e^(2x)
  return 1.0f - 2.0f * frcp(e + 1.0f);
}
__device__ __forceinline__ float fsigm(float x) {
  return frcp(1.0f + fexp2(x * -1.4426950408889634f));
}
__device__ __forceinline__ unsigned short f2bf(float f) {   // RNE bf16
  unsigned u = __float_as_uint(f);
  u += 0x7FFFu + ((u >> 16) & 1u);
  return (unsigned short)(u >> 16);
}
__device__ __forceinline__ float bf2f(unsigned short s) {
  return __uint_as_float((unsigned)s << 16);
}

// ---------------- one-time weight transposes (W[r][k] -> Wt[k*R + r]) -------
__global__ void k_transpose(const float* s0, const float* s1, const float* s2,
                            const float* s3, const float* s4, const float* s5,
                            const float* s6, const float* s7, const float* s8,
                            float* d0, float* d1, float* d2, float* d3,
                            float* d4, float* d5, float* d6, float* d7,
                            float* d8) {
  const float* src; float* dst; int R, Cd;
  switch (blockIdx.y) {
    case 0:  src = s0; dst = d0; R = 128;  Cd = 300; break;  // W_td3
    case 1:  src = s1; dst = d1; R = 128;  Cd = 512; break;  // W_td1
    case 2:  src = s2; dst = d2; R = 128;  Cd = 128; break;  // W_td
    case 3:  src = s3; dst = d3; R = 128;  Cd = 128; break;  // W_l1
    case 4:  src = s4; dst = d4; R = 128;  Cd = 512; break;  // W_l2
    case 5:  src = s5; dst = d5; R = 128;  Cd = 128; break;  // W_l
    case 6:  src = s6; dst = d6; R = 1536; Cd = 128; break;  // W1_ih
    case 7:  src = s7; dst = d7; R = 1536; Cd = 128; break;  // W2_ih
    default: src = s8; dst = d8; R = 512;  Cd = 512; break;  // W_hidd
  }
  int n = R * Cd;
  for (int i = blockIdx.x * blockDim.x + threadIdx.x; i < n;
       i += gridDim.x * blockDim.x) {
    int k = i / R, r = i - k * R;
    dst[i] = src[r * Cd + k];    // dst[k*R + r]
  }
}

// ---------------- bf16 copies of the loop-local transposed weights -----------
__global__ void k_tobf16(const float* s0, const float* s1, const float* s2,
                         const float* s3, const float* s4, const float* s5,
                         const float* s6, const float* s7,
                         unsigned short* d0, unsigned short* d1,
                         unsigned short* d2, unsigned short* d3,
                         unsigned short* d4, unsigned short* d5,
                         unsigned short* d6, unsigned short* d7) {
  const float* s; unsigned short* d; int n;
  switch (blockIdx.y) {
    case 0:  s = s0; d = d0; n = kC * kC; break;   // l1t
    case 1:  s = s1; d = d1; n = kH * kC; break;   // l2t
    case 2:  s = s2; d = d2; n = kC * kC; break;   // lt
    case 3:  s = s3; d = d3; n = kC * kG; break;   // iht2
    case 4:  s = s4; d = d4; n = kH * kH; break;   // whd_t
    case 5:  s = s5; d = d5; n = kH * kC; break;   // td1t
    case 6:  s = s6; d = d6; n = kC * kC; break;   // tdt
    default: s = s7; d = d7; n = kC * kG; break;   // iht1
  }
  for (int i = blockIdx.x * blockDim.x + threadIdx.x; i < n;
       i += gridDim.x * blockDim.x)
    d[i] = f2bf(s[i]);
}

// ---------------- one-time weight hi/lo bf16 splits --------------------------
__global__ void k_split(const float* s0, const float* s1, const float* s2,
                        const float* s3,
                        unsigned short* h0, unsigned short* l0,
                        unsigned short* h1, unsigned short* l1,
                        unsigned short* h2, unsigned short* l2,
                        unsigned short* h3, unsigned short* l3) {
  const float* s; unsigned short* h; unsigned short* l; int n;
  switch (blockIdx.y) {
    case 0:  s = s0; h = h0; l = l0; n = kG * kH; break;   // W1_hh
    case 1:  s = s1; h = h1; l = l1; n = kG * kH; break;   // W2_hh
    case 2:  s = s2; h = h2; l = l2; n = kV * kH; break;   // W_cls
    default: s = s3; h = h3; l = l3; n = kH * kC; break;   // W_feat
  }
  for (int i = blockIdx.x * blockDim.x + threadIdx.x; i < n;
       i += gridDim.x * blockDim.x) {
    float v = s[i];
    unsigned short hb = f2bf(v);
    h[i] = hb;
    l[i] = f2bf(v - bf2f(hb));
  }
}

// ---------------- init: td = t_feat @ W_td2^T ; zero h states ----------------
__global__ void k_init(const float* __restrict__ t_feat,
                       const float* __restrict__ W_td2,
                       float* __restrict__ td, float* __restrict__ h1,
                       float* __restrict__ h2,
                       unsigned short* __restrict__ h1h,
                       unsigned short* __restrict__ h1l,
                       unsigned short* __restrict__ h2h,
                       unsigned short* __restrict__ h2l) {
  int tid = blockIdx.x * 256 + threadIdx.x;  // 32768 threads
  int b = tid >> 7, c = tid & 127;
  const float* tf = t_feat + b * kC;
  const float* w  = W_td2 + c * kC;
  float acc = 0.f;
  for (int k = 0; k < kC; ++k) acc = fmaf(tf[k], w[k], acc);
  td[tid] = acc;
  for (int i = tid; i < kB * kH; i += (1 << 15)) {
    h1[i] = 0.f; h2[i] = 0.f;
    h1h[i] = 0; h1l[i] = 0; h2h[i] = 0; h2l[i] = 0;
  }
}

// ---------------- xw[t][b][:] = x_t @ W_td3^T + td ---------------------------
__global__ __launch_bounds__(256) void k_xw(
    const float* __restrict__ word_embs, const float* __restrict__ td3t,
    const float* __restrict__ td, float* __restrict__ xw) {
  __shared__ float xl[4 * 300];
  __shared__ float tdl[512];
  int t = blockIdx.y, b0 = blockIdx.x * 4, tid = threadIdx.x;
  #pragma unroll
  for (int r = 0; r < 4; ++r) {
    const float* xs = word_embs + (size_t)(b0 + r) * (kT * kE) + (size_t)t * kE;
    for (int e = tid; e < kE; e += 256) xl[r * kE + e] = xs[e];
  }
  for (int i = tid; i < 512; i += 256) tdl[i] = td[(size_t)b0 * kC + i];
  __syncthreads();
  #pragma unroll
  for (int q = 0; q < 2; ++q) {
    int idx = tid + q * 256;
    int r = idx >> 7, c = idx & 127;
    float acc = tdl[idx];
    const float* xr = xl + r * kE;
    const float* w3 = td3t + c;
    for (int e = 0; e < kE; ++e) acc = fmaf(xr[e], w3[(size_t)e * 128], acc);
    xw[((size_t)t * kB + b0 + r) * kC + c] = acc;
  }
}

// ---------------- prestep: gx1(0) from xw[0] (h2 = 0) ------------------------
__global__ __launch_bounds__(256) void k_prestep(
    const float* __restrict__ xw, const unsigned short* __restrict__ tdbt,
    const unsigned short* __restrict__ iht1b, const float* __restrict__ b1_ih,
    float* __restrict__ gx1) {
  __shared__ float s1l[128];
  __shared__ float s2l[128];
  __shared__ float part[256];
  int b = blockIdx.x, tid = threadIdx.x;
  if (tid < 128) s1l[tid] = ftanh(xw[(size_t)b * kC + tid]);
  __syncthreads();
  {
    int c = tid & 127, g = tid >> 7;
    float s = 0.f;
    const unsigned short* w = tdbt + (size_t)(g * 64) * kC + c;
    for (int k = 0; k < 64; ++k)
      s = fmaf(s1l[g * 64 + k], bf2f(w[(size_t)k * kC]), s);
    part[g * 128 + c] = s;
  }
  __syncthreads();
  if (tid < 128) s2l[tid] = fmaxf(part[tid] + part[128 + tid], 0.f);
  __syncthreads();
  #pragma unroll
  for (int q = 0; q < 6; ++q) {
    int j = q * 256 + tid;
    float acc = b1_ih[j];
    const unsigned short* w = iht1b + j;
    for (int k = 0; k < kC; ++k)
      acc = fmaf(s2l[k], bf2f(w[(size_t)k * kG]), acc);
    gx1[(size_t)b * kG + j] = acc;
  }
}

// ---------------- LDS-staged split-bf16 MFMA 128x128 tile (3-term) -----------
// 256 threads. Stages 128x32 bf16 tiles; 16B slot XOR-swizzled by (row>>1)&3
// so quarter-wave ds_read_b128 spreads over 8 bank-starts (2-way max = free).
// Verified round 10: SQ_LDS_BANK_CONFLICT == 0.
__device__ __forceinline__ void mm_tile_lds(
    const unsigned short* __restrict__ Ah, const unsigned short* __restrict__ Al,
    const unsigned short* __restrict__ Bh, const unsigned short* __restrict__ Bl,
    int m0, int n0, int K, int kbeg, int kend, int nMax, f32x4 acc[4][4],
    unsigned short* sAh, unsigned short* sAl,
    unsigned short* sBh, unsigned short* sBl) {
  int tid = threadIdx.x;
  int lane = tid & 63, wid = tid >> 6;
  int wm = (wid >> 1) * 64, wn = (wid & 1) * 64;
  int r16 = lane & 15, kq = lane >> 4;
  int rA = tid >> 2;
  int swSlot = (((tid & 3) ^ ((rA >> 1) & 3)) * 8);   // write-side swizzle
  int cA = (tid & 3) * 8;                             // global k-chunk
  int swr = (kq ^ ((r16 >> 1) & 3)) * 8;              // read-side swizzle
  int brow0 = n0 + rA;       if (brow0 > nMax) brow0 = nMax;
  int brow1 = n0 + rA + 64;  if (brow1 > nMax) brow1 = nMax;
  for (int k0 = kbeg; k0 < kend; k0 += 32) {
    uint4 va0 = *(const uint4*)(Ah + (size_t)(m0 + rA) * K + k0 + cA);
    uint4 va1 = *(const uint4*)(Ah + (size_t)(m0 + rA + 64) * K + k0 + cA);
    uint4 vb0 = *(const uint4*)(Al + (size_t)(m0 + rA) * K + k0 + cA);
    uint4 vb1 = *(const uint4*)(Al + (size_t)(m0 + rA + 64) * K + k0 + cA);
    uint4 vc0 = *(const uint4*)(Bh + (size_t)brow0 * K + k0 + cA);
    uint4 vc1 = *(const uint4*)(Bh + (size_t)brow1 * K + k0 + cA);
    uint4 vd0 = *(const uint4*)(Bl + (size_t)brow0 * K + k0 + cA);
    uint4 vd1 = *(const uint4*)(Bl + (size_t)brow1 * K + k0 + cA);
    __syncthreads();   // previous chunk's reads complete
    *(uint4*)&sAh[rA * 32 + swSlot] = va0;
    *(uint4*)&sAh[(rA + 64) * 32 + swSlot] = va1;   // (rA+64)>>1 & 3 == (rA>>1)&3
    *(uint4*)&sAl[rA * 32 + swSlot] = vb0;
    *(uint4*)&sAl[(rA + 64) * 32 + swSlot] = vb1;
    *(uint4*)&sBh[rA * 32 + swSlot] = vc0;
    *(uint4*)&sBh[(rA + 64) * 32 + swSlot] = vc1;
    *(uint4*)&sBl[rA * 32 + swSlot] = vd0;
    *(uint4*)&sBl[(rA + 64) * 32 + swSlot] = vd1;
    __syncthreads();
    bf16x8 ah[4], al[4], bh[4], bl[4];
    #pragma unroll
    for (int i = 0; i < 4; ++i) {
      int ar = (wm + i * 16 + r16) * 32 + swr;
      int br = (wn + i * 16 + r16) * 32 + swr;
      ah[i] = *(const bf16x8*)&sAh[ar];
      al[i] = *(const bf16x8*)&sAl[ar];
      bh[i] = *(const bf16x8*)&sBh[br];
      bl[i] = *(const bf16x8*)&sBl[br];
    }
    #pragma unroll
    for (int i = 0; i < 4; ++i)
      #pragma unroll
      for (int j = 0; j < 4; ++j) {
        acc[i][j] = __builtin_amdgcn_mfma_f32_16x16x32_bf16(ah[i], bh[j], acc[i][j], 0, 0, 0);
        acc[i][j] = __builtin_amdgcn_mfma_f32_16x16x32_bf16(ah[i], bl[j], acc[i][j], 0, 0, 0);
        acc[i][j] = __builtin_amdgcn_mfma_f32_16x16x32_bf16(al[i], bh[j], acc[i][j], 0, 0, 0);
      }
  }
}

// ---------------- feat_proj = c_feats @ W_feat^T -> bf16 (MFMA) --------------
__global__ __launch_bounds__(256) void k_featproj(
    const float* __restrict__ A, const unsigned short* __restrict__ Wh,
    const unsigned short* __restrict__ Wl, unsigned short* __restrict__ out) {
  int lane = threadIdx.x & 63, wid = threadIdx.x >> 6;
  int wm = (wid >> 1) * 64, wn = (wid & 1) * 64;
  int r16 = lane & 15, kq = lane >> 4;
  int m0 = blockIdx.x * 128, n0 = blockIdx.y * 128;
  f32x4 acc[4][4];
  #pragma unroll
  for (int i = 0; i < 4; ++i)
    #pragma unroll
    for (int j = 0; j < 4; ++j) acc[i][j] = (f32x4){0.f, 0.f, 0.f, 0.f};
  for (int k0 = 0; k0 < kC; k0 += 32) {
    int kk = k0 + kq * 8;
    bf16x8 ah[4], al[4], bh[4], bl[4];
    #pragma unroll
    for (int i = 0; i < 4; ++i) {
      const float* pa = A + (size_t)(m0 + wm + i * 16 + r16) * kC + kk;
      float4 v0 = *(const float4*)pa;
      float4 v1 = *(const float4*)(pa + 4);
      float vv[8] = {v0.x, v0.y, v0.z, v0.w, v1.x, v1.y, v1.z, v1.w};
      union { unsigned short s[8]; bf16x8 v; } uh, ul;
      #pragma unroll
      for (int q = 0; q < 8; ++q) {
        unsigned short hb = f2bf(vv[q]);
        uh.s[q] = hb;
        ul.s[q] = f2bf(vv[q] - bf2f(hb));
      }
      ah[i] = uh.v; al[i] = ul.v;
      const unsigned short* pb = Wh + (size_t)(n0 + wn + i * 16 + r16) * kC + kk;
      const unsigned short* pl = Wl + (size_t)(n0 + wn + i * 16 + r16) * kC + kk;
      union { uint4 u; bf16x8 v; } xb, xl2;
      xb.u = *(const uint4*)pb; xl2.u = *(const uint4*)pl;
      bh[i] = xb.v; bl[i] = xl2.v;
    }
    #pragma unroll
    for (int i = 0; i < 4; ++i)
      #pragma unroll
      for (int j = 0; j < 4; ++j) {
        acc[i][j] = __builtin_amdgcn_mfma_f32_16x16x32_bf16(ah[i], bh[j], acc[i][j], 0, 0, 0);
        acc[i][j] = __builtin_amdgcn_mfma_f32_16x16x32_bf16(ah[i], bl[j], acc[i][j], 0, 0, 0);
        acc[i][j] = __builtin_amdgcn_mfma_f32_16x16x32_bf16(al[i], bh[j], acc[i][j], 0, 0, 0);
      }
  }
  #pragma unroll
  for (int i = 0; i < 4; ++i)
    #pragma unroll
    for (int j = 0; j < 4; ++j)
      #pragma unroll
      for (int r = 0; r < 4; ++r) {
        int m = m0 + wm + i * 16 + kq * 4 + r;
        int n = n0 + wn + j * 16 + r16;
        out[(size_t)m * kH + n] = f2bf(acc[i][j][r]);
      }
}

// ---------------- per-step kernel 1: gh1/gh2 MFMA, K-split x2 (96 blocks) ----
__global__ __launch_bounds__(256) void k_gh(
    const unsigned short* __restrict__ h1h, const unsigned short* __restrict__ h1l,
    const unsigned short* __restrict__ h2h, const unsigned short* __restrict__ h2l,
    const unsigned short* __restrict__ w1hh_h, const unsigned short* __restrict__ w1hh_l,
    const unsigned short* __restrict__ w2hh_h, const unsigned short* __restrict__ w2hh_l,
    const float* __restrict__ b1_hh, const float* __restrict__ b2_hh,
    float* __restrict__ gh1, float* __restrict__ gh2) {
  __shared__ __align__(16) unsigned short sAh[4096], sAl[4096], sBh[4096], sBl[4096];
  int g2 = blockIdx.x;          // 0..95
  int half = g2 & 1, g = g2 >> 1;   // g 0..47
  const unsigned short *Ah, *Al, *Wh, *Wl; const float* bias; float* out;
  if (g < 24) { Ah = h1h; Al = h1l; Wh = w1hh_h; Wl = w1hh_l;
                bias = b1_hh; out = gh1; }
  else { g -= 24; Ah = h2h; Al = h2l; Wh = w2hh_h; Wl = w2hh_l;
         bias = b2_hh; out = gh2; }
  out += (size_t)half * (kB * kG);
  int m0 = (g / 12) * 128, n0 = (g % 12) * 128;
  f32x4 acc[4][4];
  #pragma unroll
  for (int i = 0; i < 4; ++i)
    #pragma unroll
    for (int j = 0; j < 4; ++j) acc[i][j] = (f32x4){0.f, 0.f, 0.f, 0.f};
  mm_tile_lds(Ah, Al, Wh, Wl, m0, n0, kH, half * 256, half * 256 + 256,
              kG - 1, acc, sAh, sAl, sBh, sBl);
  int tid = threadIdx.x;
  int lane = tid & 63, wid = tid >> 6;
  int wm = (wid >> 1) * 64, wn = (wid & 1) * 64;
  int r16 = lane & 15, kq = lane >> 4;
  #pragma unroll
  for (int i = 0; i < 4; ++i)
    #pragma unroll
    for (int j = 0; j < 4; ++j)
      #pragma unroll
      for (int r = 0; r < 4; ++r) {
        int m = m0 + wm + i * 16 + kq * 4 + r;
        int n = n0 + wn + j * 16 + r16;
        float v = acc[i][j][r];
        if (half == 0) v += bias[n];
        out[(size_t)m * kG + n] = v;
      }
}

// ---------------- per-step kernel 2: one batch row per block, 1024 threads ---
__global__ __launch_bounds__(1024, 4) void k_step2(
    float* __restrict__ gx1, const float* __restrict__ gh1,
    const float* __restrict__ gh2,
    float* __restrict__ h1, float* __restrict__ h2,
    unsigned short* __restrict__ h1h, unsigned short* __restrict__ h1l,
    unsigned short* __restrict__ h2h, unsigned short* __restrict__ h2l,
    const unsigned short* __restrict__ whdbT, const float* __restrict__ W_att,
    const unsigned short* __restrict__ fp, const float* __restrict__ c_feats,
    const unsigned short* __restrict__ l1bt, const unsigned short* __restrict__ l2bt,
    const unsigned short* __restrict__ lbt, const unsigned short* __restrict__ iht2b,
    const float* __restrict__ b2_ih,
    const unsigned short* __restrict__ td1bt, const unsigned short* __restrict__ tdbt,
    const unsigned short* __restrict__ iht1b, const float* __restrict__ b1_ih,
    const float* __restrict__ xw,
    unsigned short* __restrict__ h2all_h, unsigned short* __restrict__ h2all_l,
    float* __restrict__ mask_ws, int t) {
  __shared__ float partbuf[8192];     // 32 KB, reused across phases
  __shared__ float h1p[512];
  __shared__ float h2p[512];
  __shared__ float hqs[512];
  __shared__ float scs[256];
  __shared__ float red[16];
  __shared__ float red2[16];
  __shared__ float attl[128];
  __shared__ float lt1[128];
  __shared__ float llv[128];
  __shared__ float s1l[128];
  __shared__ float s2l[128];
  __shared__ float gx2l[1536];
  const int b = blockIdx.x;
  const int tid = threadIdx.x;
  const int lane = tid & 63, wv = tid >> 6;   // 16 waves
  const size_t GPART = (size_t)kB * kG;       // gh k-split partial offset

  // ---- A: GRU1 combine -> h1' ----
  if (tid < 512) {
    int c = tid;
    float gr = gx1[(size_t)b * kG + c];
    float gz = gx1[(size_t)b * kG + 512 + c];
    float gn = gx1[(size_t)b * kG + 1024 + c];
    float hr = gh1[(size_t)b * kG + c] + gh1[GPART + (size_t)b * kG + c];
    float hz = gh1[(size_t)b * kG + 512 + c] + gh1[GPART + (size_t)b * kG + 512 + c];
    float hnv = gh1[(size_t)b * kG + 1024 + c] + gh1[GPART + (size_t)b * kG + 1024 + c];
    float rr = fsigm(gr + hr);
    float zz = fsigm(gz + hz);
    float nn = ftanh(gn + rr * hnv);
    float ho = h1[(size_t)b * kH + c];
    float hn = (1.f - zz) * nn + zz * ho;
    h1[(size_t)b * kH + c] = hn;
    h1p[c] = hn;
    unsigned short hb = f2bf(hn);
    h1h[(size_t)b * kH + c] = hb;
    h1l[(size_t)b * kH + c] = f2bf(hn - bf2f(hb));
  }
  __syncthreads();

  // ---- B: hq = h1' @ W_hidd^T. 64 col-groups(8) x 16 k-groups(32) ----
  {
    int cg = tid & 63, kg = tid >> 6;   // kg 0..15
    int c0 = cg * 8;
    const unsigned short* w = whdbT + (size_t)(kg * 32) * kH + c0;
    float acc[8] = {};
    #pragma unroll 4
    for (int k = 0; k < 32; ++k) {
      union { uint4 u; unsigned short s[8]; } wu;
      wu.u = *(const uint4*)(w + (size_t)k * kH);
      float h = h1p[kg * 32 + k];
      #pragma unroll
      for (int j = 0; j < 8; ++j) acc[j] = fmaf(h, bf2f(wu.s[j]), acc[j]);
    }
    float* pp = &partbuf[kg * 512 + c0];
    #pragma unroll
    for (int j = 0; j < 8; ++j) pp[j] = acc[j];
  }
  __syncthreads();
  if (tid < 512) {
    float s = 0.f;
    #pragma unroll
    for (int g = 0; g < 16; ++g) s += partbuf[g * 512 + tid];
    hqs[tid] = s;
  }
  __syncthreads();

  // ---- C: attention scores (exp-tanh), 16 waves x 16 proposals ----
  {
    float hq8[8], aw[8];
    #pragma unroll
    for (int j = 0; j < 8; ++j) hq8[j] = hqs[lane * 8 + j];
    {
      float4 a0 = *(const float4*)(W_att + lane * 8);
      float4 a1 = *(const float4*)(W_att + lane * 8 + 4);
      aw[0] = a0.x; aw[1] = a0.y; aw[2] = a0.z; aw[3] = a0.w;
      aw[4] = a1.x; aw[5] = a1.y; aw[6] = a1.z; aw[7] = a1.w;
    }
    const unsigned short* fpb = fp + (size_t)b * kP * kH;
    int p0 = wv * 16;
    uint4 rv = *(const uint4*)(fpb + (size_t)p0 * kH + lane * 8);
    for (int p = p0; p < p0 + 16; ++p) {
      union { uint4 v; unsigned short s[8]; } u; u.v = rv;
      if (p + 1 < p0 + 16)
        rv = *(const uint4*)(fpb + (size_t)(p + 1) * kH + lane * 8);
      float sc = 0.f;
      #pragma unroll
      for (int j = 0; j < 8; ++j) {
        float f = __uint_as_float((unsigned)u.s[j] << 16);
        sc += aw[j] * ftanh(f + hq8[j]);
      }
      #pragma unroll
      for (int m = 32; m; m >>= 1) sc += __shfl_xor(sc, m, 64);
      if (lane == 0) scs[p] = sc;
    }
  }
  __syncthreads();

  // ---- D: softmax over 256 proposals ----
  {
    float sv = (tid < 256) ? scs[tid] : -1e30f;
    float mx = sv;
    #pragma unroll
    for (int m = 32; m; m >>= 1) mx = fmaxf(mx, __shfl_xor(mx, m, 64));
    if (lane == 0) red[wv] = mx;
    __syncthreads();
    float bm = red[0];
    #pragma unroll
    for (int i = 1; i < 16; ++i) bm = fmaxf(bm, red[i]);
    float ev = (tid < 256) ? fexp2((sv - bm) * 1.4426950408889634f) : 0.f;
    float sm = ev;
    #pragma unroll
    for (int m = 32; m; m >>= 1) sm += __shfl_xor(sm, m, 64);
    if (lane == 0) red2[wv] = sm;
    __syncthreads();
    float tot = 0.f;
    #pragma unroll
    for (int i = 0; i < 16; ++i) tot += red2[i];
    if (tid < 256) {
      float mk = ev * frcp(tot);
      scs[tid] = mk;
      mask_ws[(size_t)t * (kB * kP) + (size_t)b * kP + tid] = mk;
    }
  }
  __syncthreads();

  // ---- E: attended = mask @ c_feats, 8 proposal-groups x 32 ----
  {
    int c = tid & 127, q = tid >> 7;
    const float* cf = c_feats + ((size_t)b * kP + q * 32) * kC + c;
    const float* ms = scs + q * 32;
    float acc = 0.f;
    for (int p = 0; p < 32; ++p) acc = fmaf(ms[p], cf[(size_t)p * kC], acc);
    partbuf[q * 128 + c] = acc;
  }
  __syncthreads();
  if (tid < 128) {
    float s = 0.f;
    #pragma unroll
    for (int q = 0; q < 8; ++q) s += partbuf[q * 128 + tid];
    attl[tid] = s;
  }
  __syncthreads();

  // ---- F: lt1 = tanh(att@W_l1^T + h1'@W_l2^T) ----
  {
    if (tid < 512) {
      int cg = tid & 15, kg = tid >> 4;
      int c0 = cg * 8;
      const unsigned short* w = l2bt + (size_t)(kg * 16) * kC + c0;
      float acc[8] = {};
      for (int k = 0; k < 16; ++k) {
        union { uint4 u; unsigned short s[8]; } wu;
        wu.u = *(const uint4*)(w + (size_t)k * kC);
        float h = h1p[kg * 16 + k];
        #pragma unroll
        for (int j = 0; j < 8; ++j) acc[j] = fmaf(h, bf2f(wu.s[j]), acc[j]);
      }
      float* pp = &partbuf[kg * 128 + c0];
      #pragma unroll
      for (int j = 0; j < 8; ++j) pp[j] = acc[j];
    } else if (tid < 768) {
      int tt = tid - 512;
      int cg = tt & 15, kg = tt >> 4;
      int c0 = cg * 8;
      const unsigned short* w = l1bt + (size_t)(kg * 8) * kC + c0;
      float acc[8] = {};
      for (int k = 0; k < 8; ++k) {
        union { uint4 u; unsigned short s[8]; } wu;
        wu.u = *(const uint4*)(w + (size_t)k * kC);
        float a = attl[kg * 8 + k];
        #pragma unroll
        for (int j = 0; j < 8; ++j) acc[j] = fmaf(a, bf2f(wu.s[j]), acc[j]);
      }
      float* pp = &partbuf[4096 + kg * 128 + c0];
      #pragma unroll
      for (int j = 0; j < 8; ++j) pp[j] = acc[j];
    }
  }
  __syncthreads();
  if (tid < 128) {
    float s = 0.f;
    #pragma unroll
    for (int g = 0; g < 32; ++g) s += partbuf[g * 128 + tid];
    #pragma unroll
    for (int g = 0; g < 16; ++g) s += partbuf[4096 + g * 128 + tid];
    lt1[tid] = ftanh(s);
  }
  __syncthreads();

  // ---- G: llv = relu(lt1 @ W_l^T), 16 cg x 16 kg (k=8) ----
  if (tid < 256) {
    int cg = tid & 15, kg = tid >> 4;
    int c0 = cg * 8;
    const unsigned short* w = lbt + (size_t)(kg * 8) * kC + c0;
    float acc[8] = {};
    for (int k = 0; k < 8; ++k) {
      union { uint4 u; unsigned short s[8]; } wu;
      wu.u = *(const uint4*)(w + (size_t)k * kC);
      float l = lt1[kg * 8 + k];
      #pragma unroll
      for (int j = 0; j < 8; ++j) acc[j] = fmaf(l, bf2f(wu.s[j]), acc[j]);
    }
    float* pp = &partbuf[kg * 128 + c0];
    #pragma unroll
    for (int j = 0; j < 8; ++j) pp[j] = acc[j];
  }
  __syncthreads();
  if (tid < 128) {
    float s = 0.f;
    #pragma unroll
    for (int g = 0; g < 16; ++g) s += partbuf[g * 128 + tid];
    llv[tid] = fmaxf(s, 0.f);
  }
  __syncthreads();

  // ---- H: gx2 = llv @ W2_ih^T + b2. 192 cg(8) x 4 kg(32) ----
  if (tid < 768) {
    int cg = tid % 192, kg = tid / 192;
    int c0 = cg * 8;
    const unsigned short* w = iht2b + (size_t)(kg * 32) * kG + c0;
    float acc[8] = {};
    #pragma unroll 4
    for (int k = 0; k < 32; ++k) {
      union { uint4 u; unsigned short s[8]; } wu;
      wu.u = *(const uint4*)(w + (size_t)k * kG);
      float l = llv[kg * 32 + k];
      #pragma unroll
      for (int j = 0; j < 8; ++j) acc[j] = fmaf(l, bf2f(wu.s[j]), acc[j]);
    }
    float* pp = &partbuf[kg * 1536 + c0];
    #pragma unroll
    for (int j = 0; j < 8; ++j) pp[j] = acc[j];
  }
  __syncthreads();
  for (int c = tid; c < kG; c += 1024) {
    float s = b2_ih[c];
    #pragma unroll
    for (int g = 0; g < 4; ++g) s += partbuf[g * 1536 + c];
    gx2l[c] = s;
  }
  __syncthreads();
  if (tid < 512) {
    int c = tid;
    float ghr = gh2[(size_t)b * kG + c] + gh2[GPART + (size_t)b * kG + c];
    float ghz = gh2[(size_t)b * kG + 512 + c] + gh2[GPART + (size_t)b * kG + 512 + c];
    float ghn = gh2[(size_t)b * kG + 1024 + c] + gh2[GPART + (size_t)b * kG + 1024 + c];
    float rr = fsigm(gx2l[c] + ghr);
    float zz = fsigm(gx2l[512 + c] + ghz);
    float nn = ftanh(gx2l[1024 + c] + rr * ghn);
    float ho = h2[(size_t)b * kH + c];
    float hn = (1.f - zz) * nn + zz * ho;
    h2[(size_t)b * kH + c] = hn;
    h2p[c] = hn;
    unsigned short hb = f2bf(hn);
    unsigned short lb = f2bf(hn - bf2f(hb));
    h2h[(size_t)b * kH + c] = hb;
    h2l[(size_t)b * kH + c] = lb;
    size_t o = ((size_t)t * kB + b) * kH + c;
    h2all_h[o] = hb;
    h2all_l[o] = lb;
  }
  __syncthreads();

  // ---- I: next step's s-chain + gx1 ----
  if (t + 1 < kNS) {
    // I1: s1 = tanh(xw[t+1] + h2'@W_td1^T), 16 cg x 32 kg (k=16)
    if (tid < 512) {
      int cg = tid & 15, kg = tid >> 4;
      int c0 = cg * 8;
      const unsigned short* w = td1bt + (size_t)(kg * 16) * kC + c0;
      float acc[8] = {};
      for (int k = 0; k < 16; ++k) {
        union { uint4 u; unsigned short s[8]; } wu;
        wu.u = *(const uint4*)(w + (size_t)k * kC);
        float h = h2p[kg * 16 + k];
        #pragma unroll
        for (int j = 0; j < 8; ++j) acc[j] = fmaf(h, bf2f(wu.s[j]), acc[j]);
      }
      float* pp = &partbuf[kg * 128 + c0];
      #pragma unroll
      for (int j = 0; j < 8; ++j) pp[j] = acc[j];
    }
    __syncthreads();
    if (tid < 128) {
      float s = xw[((size_t)(t + 1) * kB + b) * kC + tid];
      #pragma unroll
      for (int g = 0; g < 32; ++g) s += partbuf[g * 128 + tid];
      s1l[tid] = ftanh(s);
    }
    __syncthreads();
    // I2: s2 = relu(s1 @ W_td^T), 16 cg x 16 kg (k=8)
    if (tid < 256) {
      int cg = tid & 15, kg = tid >> 4;
      int c0 = cg * 8;
      const unsigned short* w = tdbt + (size_t)(kg * 8) * kC + c0;
      float acc[8] = {};
      for (int k = 0; k < 8; ++k) {
        union { uint4 u; unsigned short s[8]; } wu;
        wu.u = *(const uint4*)(w + (size_t)k * kC);
        float sv = s1l[kg * 8 + k];
        #pragma unroll
        for (int j = 0; j < 8; ++j) acc[j] = fmaf(sv, bf2f(wu.s[j]), acc[j]);
      }
      float* pp = &partbuf[kg * 128 + c0];
      #pragma unroll
      for (int j = 0; j < 8; ++j) pp[j] = acc[j];
    }
    __syncthreads();
    if (tid < 128) {
      float s = 0.f;
      #pragma unroll
      for (int g = 0; g < 16; ++g) s += partbuf[g * 128 + tid];
      s2l[tid] = fmaxf(s, 0.f);
    }
    __syncthreads();
    // I3: gx1(t+1) = s2 @ W1_ih^T + b1. 192 cg(8) x 4 kg(32)
    if (tid < 768) {
      int cg = tid % 192, kg = tid / 192;
      int c0 = cg * 8;
      const unsigned short* w = iht1b + (size_t)(kg * 32) * kG + c0;
      float acc[8] = {};
      #pragma unroll 4
      for (int k = 0; k < 32; ++k) {
        union { uint4 u; unsigned short s[8]; } wu;
        wu.u = *(const uint4*)(w + (size_t)k * kG);
        float sv = s2l[kg * 32 + k];
        #pragma unroll
        for (int j = 0; j < 8; ++j) acc[j] = fmaf(sv, bf2f(wu.s[j]), acc[j]);
      }
      float* pp = &partbuf[kg * 1536 + c0];
      #pragma unroll
      for (int j = 0; j < 8; ++j) pp[j] = acc[j];
    }
    __syncthreads();
    for (int c = tid; c < kG; c += 1024) {
      float s = b1_ih[c];
      #pragma unroll
      for (int g = 0; g < 4; ++g) s += partbuf[g * 1536 + c];
      gx1[(size_t)b * kG + c] = s;
    }
  }
}

// ---------------- mask transpose via LDS: [t][b][p] -> out[b][p][t] ----------
__global__ __launch_bounds__(256) void k_atrans(
    const float* __restrict__ mws, float* __restrict__ attn_out) {
  __shared__ float tile[256][33];
  int pair0 = blockIdx.x * 256;     // 256 blocks cover 65536 (b,p) pairs
  int tid = threadIdx.x;
  #pragma unroll
  for (int t = 0; t < kNS; ++t)
    tile[tid][t] = mws[(size_t)t * (kB * kP) + pair0 + tid];
  __syncthreads();
  float* outb = attn_out + (size_t)pair0 * kNS;
  #pragma unroll
  for (int i = 0; i < kNS; ++i) {
    int g = i * 256 + tid;           // 0..7935 contiguous output floats
    int pr = g / 31, tt = g - pr * 31;
    outb[g] = tile[pr][tt];
  }
}

// ---------------- classifier: lang = h2_all @ W_cls^T + b_cls (MFMA, LDS) ----
// XCD-aware bijective block swizzle (T1): consecutive blocks within one XCD
// share the same n-tile (B slice stays L2-resident) and walk m.
__global__ __launch_bounds__(256) void k_cls(
    const unsigned short* __restrict__ Ah, const unsigned short* __restrict__ Al,
    const unsigned short* __restrict__ Wh, const unsigned short* __restrict__ Wl,
    const float* __restrict__ bc, float* __restrict__ out) {
  __shared__ __align__(16) unsigned short sAh[4096], sAl[4096], sBh[4096], sBl[4096];
  constexpr int kMT = 62, kNT = 27, kNWG = kMT * kNT;   // 1674
  constexpr int kQ = kNWG / 8, kR = kNWG % 8;           // 209, 2
  int lin = blockIdx.x;
  int xcd = lin & 7, pos = lin >> 3;
  int swz = (xcd < kR ? xcd * (kQ + 1) : kR * (kQ + 1) + (xcd - kR) * kQ) + pos;
  int n_t = swz / kMT, m_t = swz - n_t * kMT;   // m fastest within XCD chunk
  int m0 = m_t * 128, n0 = n_t * 128;
  f32x4 acc[4][4];
  #pragma unroll
  for (int i = 0; i < 4; ++i)
    #pragma unroll
    for (int j = 0; j < 4; ++j) acc[i][j] = (f32x4){0.f, 0.f, 0.f, 0.f};
  mm_tile_lds(Ah, Al, Wh, Wl, m0, n0, kH, 0, kH, kV - 1, acc,
              sAh, sAl, sBh, sBl);
  int lane = threadIdx.x & 63, wid = threadIdx.x >> 6;
  int wm = (wid >> 1) * 64, wn = (wid & 1) * 64;
  int r16 = lane & 15, kq = lane >> 4;
  #pragma unroll
  for (int i = 0; i < 4; ++i)
    #pragma unroll
    for (int j = 0; j < 4; ++j)
      #pragma unroll
      for (int r = 0; r < 4; ++r) {
        int m = m0 + wm + i * 16 + kq * 4 + r;
        int n = n0 + wn + j * 16 + r16;
        if (n < kV) {
          int tt = m >> 8, b = m & 255;
          out[(size_t)b * (kNS * kV) + (size_t)tt * kV + n] = acc[i][j][r] + bc[n];
        }
      }
}

}  // namespace

extern "C" void kernel_launch(void* const* d_in, const int* in_sizes, int n_in,
                              void* d_out, int out_size, void* d_ws,
                              size_t ws_size, hipStream_t stream) {
  (void)in_sizes; (void)n_in; (void)out_size; (void)ws_size;
  const float* word_embs = (const float*)d_in[0];
  const float* t_feat    = (const float*)d_in[1];
  const float* c_feats   = (const float*)d_in[2];
  const float* W_td1 = (const float*)d_in[4];
  const float* W_td2 = (const float*)d_in[5];
  const float* W_td3 = (const float*)d_in[6];
  const float* W_td  = (const float*)d_in[7];
  const float* W1_ih = (const float*)d_in[8];
  const float* W1_hh = (const float*)d_in[9];
  const float* b1_ih = (const float*)d_in[10];
  const float* b1_hh = (const float*)d_in[11];
  const float* W_feat = (const float*)d_in[12];
  const float* W_hidd = (const float*)d_in[13];
  const float* W_att  = (const float*)d_in[14];
  const float* W_l1 = (const float*)d_in[15];
  const float* W_l2 = (const float*)d_in[16];
  const float* W_l  = (const float*)d_in[17];
  const float* W2_ih = (const float*)d_in[18];
  const float* W2_hh = (const float*)d_in[19];
  const float* b2_ih = (const float*)d_in[20];
  const float* b2_hh = (const float*)d_in[21];
  const float* W_cls = (const float*)d_in[22];
  const float* b_cls = (const float*)d_in[23];

  float* lang = (float*)d_out;
  float* attn_out = lang + (size_t)kB * kNS * kV;
  // feat_proj (bf16, 64MB) lives in the lang_cap region of d_out — dead by
  // the time k_cls (the only writer of lang_cap) runs.
  unsigned short* fp = (unsigned short*)d_out;

  float* p = (float*)d_ws;
  float* h1 = p;      p += kB * kH;
  float* h2 = p;      p += kB * kH;
  float* td = p;      p += kB * kC;
  float* gx1 = p;     p += (size_t)kB * kG;
  float* gh1 = p;     p += (size_t)2 * kB * kG;   // 2 K-split partials
  float* gh2 = p;     p += (size_t)2 * kB * kG;
  float* mask_ws = p; p += (size_t)kNS * kB * kP;
  float* xw = p;      p += (size_t)kNS * kB * kC;
  float* td3t = p;    p += kE * 128;
  float* td1t = p;    p += kH * 128;
  float* tdt  = p;    p += 128 * 128;
  float* l1t  = p;    p += 128 * 128;
  float* l2t  = p;    p += kH * 128;
  float* lt   = p;    p += 128 * 128;
  float* iht1 = p;    p += 128 * kG;
  float* iht2 = p;    p += 128 * kG;
  float* whd_t = p;   p += kH * kH;

  unsigned short* u = (unsigned short*)p;
  unsigned short* h1h = u;     u += kB * kH;
  unsigned short* h1l = u;     u += kB * kH;
  unsigned short* h2h = u;     u += kB * kH;
  unsigned short* h2l = u;     u += kB * kH;
  unsigned short* w1hh_h = u;  u += (size_t)kG * kH;
  unsigned short* w1hh_l = u;  u += (size_t)kG * kH;
  unsigned short* w2hh_h = u;  u += (size_t)kG * kH;
  unsigned short* w2hh_l = u;  u += (size_t)kG * kH;
  unsigned short* wc_h = u;    u += (size_t)kV * kH;
  unsigned short* wc_l = u;    u += (size_t)kV * kH;
  unsigned short* wf_h = u;    u += (size_t)kH * kC;
  unsigned short* wf_l = u;    u += (size_t)kH * kC;
  unsigned short* h2all_h = u; u += (size_t)kNS * kB * kH;
  unsigned short* h2all_l = u; u += (size_t)kNS * kB * kH;
  unsigned short* l1bt = u;    u += kC * kC;
  unsigned short* l2bt = u;    u += (size_t)kH * kC;
  unsigned short* lbt = u;     u += kC * kC;
  unsigned short* iht2b = u;   u += (size_t)kC * kG;
  unsigned short* whdbT = u;   u += (size_t)kH * kH;
  unsigned short* td1bt = u;   u += (size_t)kH * kC;
  unsigned short* tdbt = u;    u += kC * kC;
  unsigned short* iht1b = u;   u += (size_t)kC * kG;

  k_transpose<<<dim3(64, 9), 256, 0, stream>>>(
      W_td3, W_td1, W_td, W_l1, W_l2, W_l, W1_ih, W2_ih, W_hidd,
      td3t, td1t, tdt, l1t, l2t, lt, iht1, iht2, whd_t);
  k_tobf16<<<dim3(96, 8), 256, 0, stream>>>(
      l1t, l2t, lt, iht2, whd_t, td1t, tdt, iht1,
      l1bt, l2bt, lbt, iht2b, whdbT, td1bt, tdbt, iht1b);
  k_split<<<dim3(256, 4), 256, 0, stream>>>(
      W1_hh, W2_hh, W_cls, W_feat,
      w1hh_h, w1hh_l, w2hh_h, w2hh_l, wc_h, wc_l, wf_h, wf_l);
  k_init<<<128, 256, 0, stream>>>(t_feat, W_td2, td, h1, h2,
                                  h1h, h1l, h2h, h2l);
  k_featproj<<<dim3(512, 4), 256, 0, stream>>>(c_feats, wf_h, wf_l, fp);
  k_xw<<<dim3(64, kNS), 256, 0, stream>>>(word_embs, td3t, td, xw);
  k_prestep<<<256, 256, 0, stream>>>(xw, tdbt, iht1b, b1_ih, gx1);

  for (int t = 0; t < kNS; ++t) {
    k_gh<<<96, 256, 0, stream>>>(h1h, h1l, h2h, h2l,
                                 w1hh_h, w1hh_l, w2hh_h, w2hh_l,
                                 b1_hh, b2_hh, gh1, gh2);
    k_step2<<<256, 1024, 0, stream>>>(gx1, gh1, gh2, h1, h2,
                                      h1h, h1l, h2h, h2l, whdbT, W_att, fp,
                                      c_feats, l1bt, l2bt, lbt, iht2b, b2_ih,
                                      td1bt, tdbt, iht1b, b1_ih, xw,
                                      h2all_h, h2all_l, mask_ws, t);
  }
  k_atrans<<<256, 256, 0, stream>>>(mask_ws, attn_out);
  k_cls<<<62 * 27, 256, 0, stream>>>(h2all_h, h2all_l, wc_h, wc_l,
                                     b_cls, lang);
}

// Round 12
// 2115.056 us; speedup vs baseline: 1.1627x; 1.0429x over previous
//
#include <hip/hip_runtime.h>
#include <hip/hip_bf16.h>

namespace {

constexpr int kB  = 256;   // batch
constexpr int kP  = 256;   // proposals
constexpr int kT  = 32;    // words
constexpr int kNS = 31;    // steps = T-1
constexpr int kV  = 3433;  // vocab
constexpr int kH  = 512;   // hidden
constexpr int kE  = 300;   // embed
constexpr int kC  = 128;   // feat dim
constexpr int kG  = 1536;  // 3H

typedef __bf16 bf16x8 __attribute__((ext_vector_type(8)));
typedef float f32x4 __attribute__((ext_vector_type(4)));

__device__ __forceinline__ float fexp2(float x) {
  float r; asm("v_exp_f32 %0, %1" : "=v"(r) : "v"(x)); return r;
}
__device__ __forceinline__ float frcp(float x) {
  float r; asm("v_rcp_f32 %0, %1" : "=v"(r) : "v"(x)); return r;
}
__device__ __forceinline__ float ftanh(float x) {
  float e = fexp2(x * 2.8853900817779268f);   // e^(2x)
  return 1.0f - 2.0f * frcp(e + 1.0f);
}
__device__ __forceinline__ float fsigm(float x) {
  return frcp(1.0f + fexp2(x * -1.4426950408889634f));
}
__device__ __forceinline__ unsigned short f2bf(float f) {   // RNE bf16
  unsigned u = __float_as_uint(f);
  u += 0x7FFFu + ((u >> 16) & 1u);
  return (unsigned short)(u >> 16);
}
__device__ __forceinline__ float bf2f(unsigned short s) {
  return __uint_as_float((unsigned)s << 16);
}

// ---------------- one-time weight transposes (W[r][k] -> Wt[k*R + r]) -------
__global__ void k_transpose(const float* s0, const float* s1, const float* s2,
                            const float* s3, const float* s4, const float* s5,
                            const float* s6, const float* s7, const float* s8,
                            float* d0, float* d1, float* d2, float* d3,
                            float* d4, float* d5, float* d6, float* d7,
                            float* d8) {
  const float* src; float* dst; int R, Cd;
  switch (blockIdx.y) {
    case 0:  src = s0; dst = d0; R = 128;  Cd = 300; break;  // W_td3
    case 1:  src = s1; dst = d1; R = 128;  Cd = 512; break;  // W_td1
    case 2:  src = s2; dst = d2; R = 128;  Cd = 128; break;  // W_td
    case 3:  src = s3; dst = d3; R = 128;  Cd = 128; break;  // W_l1
    case 4:  src = s4; dst = d4; R = 128;  Cd = 512; break;  // W_l2
    case 5:  src = s5; dst = d5; R = 128;  Cd = 128; break;  // W_l
    case 6:  src = s6; dst = d6; R = 1536; Cd = 128; break;  // W1_ih
    case 7:  src = s7; dst = d7; R = 1536; Cd = 128; break;  // W2_ih
    default: src = s8; dst = d8; R = 512;  Cd = 512; break;  // W_hidd
  }
  int n = R * Cd;
  for (int i = blockIdx.x * blockDim.x + threadIdx.x; i < n;
       i += gridDim.x * blockDim.x) {
    int k = i / R, r = i - k * R;
    dst[i] = src[r * Cd + k];    // dst[k*R + r]
  }
}

// ---------------- bf16 copies of the loop-local transposed weights -----------
__global__ void k_tobf16(const float* s0, const float* s1, const float* s2,
                         const float* s3, const float* s4, const float* s5,
                         const float* s6, const float* s7,
                         unsigned short* d0, unsigned short* d1,
                         unsigned short* d2, unsigned short* d3,
                         unsigned short* d4, unsigned short* d5,
                         unsigned short* d6, unsigned short* d7) {
  const float* s; unsigned short* d; int n;
  switch (blockIdx.y) {
    case 0:  s = s0; d = d0; n = kC * kC; break;   // l1t
    case 1:  s = s1; d = d1; n = kH * kC; break;   // l2t
    case 2:  s = s2; d = d2; n = kC * kC; break;   // lt
    case 3:  s = s3; d = d3; n = kC * kG; break;   // iht2
    case 4:  s = s4; d = d4; n = kH * kH; break;   // whd_t
    case 5:  s = s5; d = d5; n = kH * kC; break;   // td1t
    case 6:  s = s6; d = d6; n = kC * kC; break;   // tdt
    default: s = s7; d = d7; n = kC * kG; break;   // iht1
  }
  for (int i = blockIdx.x * blockDim.x + threadIdx.x; i < n;
       i += gridDim.x * blockDim.x)
    d[i] = f2bf(s[i]);
}

// ---------------- one-time weight hi/lo bf16 splits --------------------------
__global__ void k_split(const float* s0, const float* s1, const float* s2,
                        const float* s3,
                        unsigned short* h0, unsigned short* l0,
                        unsigned short* h1, unsigned short* l1,
                        unsigned short* h2, unsigned short* l2,
                        unsigned short* h3, unsigned short* l3) {
  const float* s; unsigned short* h; unsigned short* l; int n;
  switch (blockIdx.y) {
    case 0:  s = s0; h = h0; l = l0; n = kG * kH; break;   // W1_hh
    case 1:  s = s1; h = h1; l = l1; n = kG * kH; break;   // W2_hh
    case 2:  s = s2; h = h2; l = l2; n = kV * kH; break;   // W_cls
    default: s = s3; h = h3; l = l3; n = kH * kC; break;   // W_feat
  }
  for (int i = blockIdx.x * blockDim.x + threadIdx.x; i < n;
       i += gridDim.x * blockDim.x) {
    float v = s[i];
    unsigned short hb = f2bf(v);
    h[i] = hb;
    l[i] = f2bf(v - bf2f(hb));
  }
}

// ---------------- init: td = t_feat @ W_td2^T ; zero h states ----------------
__global__ void k_init(const float* __restrict__ t_feat,
                       const float* __restrict__ W_td2,
                       float* __restrict__ td, float* __restrict__ h1,
                       float* __restrict__ h2,
                       unsigned short* __restrict__ h1h,
                       unsigned short* __restrict__ h1l,
                       unsigned short* __restrict__ h2h,
                       unsigned short* __restrict__ h2l) {
  int tid = blockIdx.x * 256 + threadIdx.x;  // 32768 threads
  int b = tid >> 7, c = tid & 127;
  const float* tf = t_feat + b * kC;
  const float* w  = W_td2 + c * kC;
  float acc = 0.f;
  for (int k = 0; k < kC; ++k) acc = fmaf(tf[k], w[k], acc);
  td[tid] = acc;
  for (int i = tid; i < kB * kH; i += (1 << 15)) {
    h1[i] = 0.f; h2[i] = 0.f;
    h1h[i] = 0; h1l[i] = 0; h2h[i] = 0; h2l[i] = 0;
  }
}

// ---------------- xw[t][b][:] = x_t @ W_td3^T + td ---------------------------
__global__ __launch_bounds__(256) void k_xw(
    const float* __restrict__ word_embs, const float* __restrict__ td3t,
    const float* __restrict__ td, float* __restrict__ xw) {
  __shared__ float xl[4 * 300];
  __shared__ float tdl[512];
  int t = blockIdx.y, b0 = blockIdx.x * 4, tid = threadIdx.x;
  #pragma unroll
  for (int r = 0; r < 4; ++r) {
    const float* xs = word_embs + (size_t)(b0 + r) * (kT * kE) + (size_t)t * kE;
    for (int e = tid; e < kE; e += 256) xl[r * kE + e] = xs[e];
  }
  for (int i = tid; i < 512; i += 256) tdl[i] = td[(size_t)b0 * kC + i];
  __syncthreads();
  #pragma unroll
  for (int q = 0; q < 2; ++q) {
    int idx = tid + q * 256;
    int r = idx >> 7, c = idx & 127;
    float acc = tdl[idx];
    const float* xr = xl + r * kE;
    const float* w3 = td3t + c;
    for (int e = 0; e < kE; ++e) acc = fmaf(xr[e], w3[(size_t)e * 128], acc);
    xw[((size_t)t * kB + b0 + r) * kC + c] = acc;
  }
}

// ---------------- prestep: gx1(0) from xw[0] (h2 = 0) ------------------------
__global__ __launch_bounds__(256) void k_prestep(
    const float* __restrict__ xw, const unsigned short* __restrict__ tdbt,
    const unsigned short* __restrict__ iht1b, const float* __restrict__ b1_ih,
    float* __restrict__ gx1) {
  __shared__ float s1l[128];
  __shared__ float s2l[128];
  __shared__ float part[256];
  int b = blockIdx.x, tid = threadIdx.x;
  if (tid < 128) s1l[tid] = ftanh(xw[(size_t)b * kC + tid]);
  __syncthreads();
  {
    int c = tid & 127, g = tid >> 7;
    float s = 0.f;
    const unsigned short* w = tdbt + (size_t)(g * 64) * kC + c;
    for (int k = 0; k < 64; ++k)
      s = fmaf(s1l[g * 64 + k], bf2f(w[(size_t)k * kC]), s);
    part[g * 128 + c] = s;
  }
  __syncthreads();
  if (tid < 128) s2l[tid] = fmaxf(part[tid] + part[128 + tid], 0.f);
  __syncthreads();
  #pragma unroll
  for (int q = 0; q < 6; ++q) {
    int j = q * 256 + tid;
    float acc = b1_ih[j];
    const unsigned short* w = iht1b + j;
    for (int k = 0; k < kC; ++k)
      acc = fmaf(s2l[k], bf2f(w[(size_t)k * kG]), acc);
    gx1[(size_t)b * kG + j] = acc;
  }
}

// ---------------- LDS-staged split-bf16 MFMA 128x128 tile (2-term) -----------
// C = (Ahi+Alo) * Bhi. 256 threads. Stages 128x32 bf16 tiles; 16B slot
// XOR-swizzled by (row>>1)&3 -> zero bank conflicts (verified round 10).
__device__ __forceinline__ void mm_tile_lds(
    const unsigned short* __restrict__ Ah, const unsigned short* __restrict__ Al,
    const unsigned short* __restrict__ Bh,
    int m0, int n0, int K, int kbeg, int kend, int nMax, f32x4 acc[4][4],
    unsigned short* sAh, unsigned short* sAl, unsigned short* sBh) {
  int tid = threadIdx.x;
  int lane = tid & 63, wid = tid >> 6;
  int wm = (wid >> 1) * 64, wn = (wid & 1) * 64;
  int r16 = lane & 15, kq = lane >> 4;
  int rA = tid >> 2;
  int swSlot = (((tid & 3) ^ ((rA >> 1) & 3)) * 8);   // write-side swizzle
  int cA = (tid & 3) * 8;                             // global k-chunk
  int swr = (kq ^ ((r16 >> 1) & 3)) * 8;              // read-side swizzle
  int brow0 = n0 + rA;       if (brow0 > nMax) brow0 = nMax;
  int brow1 = n0 + rA + 64;  if (brow1 > nMax) brow1 = nMax;
  for (int k0 = kbeg; k0 < kend; k0 += 32) {
    uint4 va0 = *(const uint4*)(Ah + (size_t)(m0 + rA) * K + k0 + cA);
    uint4 va1 = *(const uint4*)(Ah + (size_t)(m0 + rA + 64) * K + k0 + cA);
    uint4 vb0 = *(const uint4*)(Al + (size_t)(m0 + rA) * K + k0 + cA);
    uint4 vb1 = *(const uint4*)(Al + (size_t)(m0 + rA + 64) * K + k0 + cA);
    uint4 vc0 = *(const uint4*)(Bh + (size_t)brow0 * K + k0 + cA);
    uint4 vc1 = *(const uint4*)(Bh + (size_t)brow1 * K + k0 + cA);
    __syncthreads();   // previous chunk's reads complete
    *(uint4*)&sAh[rA * 32 + swSlot] = va0;
    *(uint4*)&sAh[(rA + 64) * 32 + swSlot] = va1;   // (rA+64)>>1 & 3 == (rA>>1)&3
    *(uint4*)&sAl[rA * 32 + swSlot] = vb0;
    *(uint4*)&sAl[(rA + 64) * 32 + swSlot] = vb1;
    *(uint4*)&sBh[rA * 32 + swSlot] = vc0;
    *(uint4*)&sBh[(rA + 64) * 32 + swSlot] = vc1;
    __syncthreads();
    bf16x8 ah[4], al[4], bh[4];
    #pragma unroll
    for (int i = 0; i < 4; ++i) {
      int ar = (wm + i * 16 + r16) * 32 + swr;
      int br = (wn + i * 16 + r16) * 32 + swr;
      ah[i] = *(const bf16x8*)&sAh[ar];
      al[i] = *(const bf16x8*)&sAl[ar];
      bh[i] = *(const bf16x8*)&sBh[br];
    }
    #pragma unroll
    for (int i = 0; i < 4; ++i)
      #pragma unroll
      for (int j = 0; j < 4; ++j) {
        acc[i][j] = __builtin_amdgcn_mfma_f32_16x16x32_bf16(ah[i], bh[j], acc[i][j], 0, 0, 0);
        acc[i][j] = __builtin_amdgcn_mfma_f32_16x16x32_bf16(al[i], bh[j], acc[i][j], 0, 0, 0);
      }
  }
}

// ---------------- feat_proj = c_feats @ W_feat^T -> bf16 (MFMA, 2-term) ------
__global__ __launch_bounds__(256) void k_featproj(
    const float* __restrict__ A, const unsigned short* __restrict__ Wh,
    unsigned short* __restrict__ out) {
  int lane = threadIdx.x & 63, wid = threadIdx.x >> 6;
  int wm = (wid >> 1) * 64, wn = (wid & 1) * 64;
  int r16 = lane & 15, kq = lane >> 4;
  int m0 = blockIdx.x * 128, n0 = blockIdx.y * 128;
  f32x4 acc[4][4];
  #pragma unroll
  for (int i = 0; i < 4; ++i)
    #pragma unroll
    for (int j = 0; j < 4; ++j) acc[i][j] = (f32x4){0.f, 0.f, 0.f, 0.f};
  for (int k0 = 0; k0 < kC; k0 += 32) {
    int kk = k0 + kq * 8;
    bf16x8 ah[4], al[4], bh[4];
    #pragma unroll
    for (int i = 0; i < 4; ++i) {
      const float* pa = A + (size_t)(m0 + wm + i * 16 + r16) * kC + kk;
      float4 v0 = *(const float4*)pa;
      float4 v1 = *(const float4*)(pa + 4);
      float vv[8] = {v0.x, v0.y, v0.z, v0.w, v1.x, v1.y, v1.z, v1.w};
      union { unsigned short s[8]; bf16x8 v; } uh, ul;
      #pragma unroll
      for (int q = 0; q < 8; ++q) {
        unsigned short hb = f2bf(vv[q]);
        uh.s[q] = hb;
        ul.s[q] = f2bf(vv[q] - bf2f(hb));
      }
      ah[i] = uh.v; al[i] = ul.v;
      const unsigned short* pb = Wh + (size_t)(n0 + wn + i * 16 + r16) * kC + kk;
      union { uint4 u; bf16x8 v; } xb;
      xb.u = *(const uint4*)pb;
      bh[i] = xb.v;
    }
    #pragma unroll
    for (int i = 0; i < 4; ++i)
      #pragma unroll
      for (int j = 0; j < 4; ++j) {
        acc[i][j] = __builtin_amdgcn_mfma_f32_16x16x32_bf16(ah[i], bh[j], acc[i][j], 0, 0, 0);
        acc[i][j] = __builtin_amdgcn_mfma_f32_16x16x32_bf16(al[i], bh[j], acc[i][j], 0, 0, 0);
      }
  }
  #pragma unroll
  for (int i = 0; i < 4; ++i)
    #pragma unroll
    for (int j = 0; j < 4; ++j)
      #pragma unroll
      for (int r = 0; r < 4; ++r) {
        int m = m0 + wm + i * 16 + kq * 4 + r;
        int n = n0 + wn + j * 16 + r16;
        out[(size_t)m * kH + n] = f2bf(acc[i][j][r]);
      }
}

// ---------------- per-step kernel 1: gh1/gh2 MFMA, K-split x2 (96 blocks) ----
__global__ __launch_bounds__(256) void k_gh(
    const unsigned short* __restrict__ h1h, const unsigned short* __restrict__ h1l,
    const unsigned short* __restrict__ h2h, const unsigned short* __restrict__ h2l,
    const unsigned short* __restrict__ w1hh_h, const unsigned short* __restrict__ w2hh_h,
    const float* __restrict__ b1_hh, const float* __restrict__ b2_hh,
    float* __restrict__ gh1, float* __restrict__ gh2) {
  __shared__ __align__(16) unsigned short sAh[4096], sAl[4096], sBh[4096];
  int g2 = blockIdx.x;          // 0..95
  int half = g2 & 1, g = g2 >> 1;   // g 0..47
  const unsigned short *Ah, *Al, *Wh; const float* bias; float* out;
  if (g < 24) { Ah = h1h; Al = h1l; Wh = w1hh_h; bias = b1_hh; out = gh1; }
  else { g -= 24; Ah = h2h; Al = h2l; Wh = w2hh_h; bias = b2_hh; out = gh2; }
  out += (size_t)half * (kB * kG);
  int m0 = (g / 12) * 128, n0 = (g % 12) * 128;
  f32x4 acc[4][4];
  #pragma unroll
  for (int i = 0; i < 4; ++i)
    #pragma unroll
    for (int j = 0; j < 4; ++j) acc[i][j] = (f32x4){0.f, 0.f, 0.f, 0.f};
  mm_tile_lds(Ah, Al, Wh, m0, n0, kH, half * 256, half * 256 + 256,
              kG - 1, acc, sAh, sAl, sBh);
  int tid = threadIdx.x;
  int lane = tid & 63, wid = tid >> 6;
  int wm = (wid >> 1) * 64, wn = (wid & 1) * 64;
  int r16 = lane & 15, kq = lane >> 4;
  #pragma unroll
  for (int i = 0; i < 4; ++i)
    #pragma unroll
    for (int j = 0; j < 4; ++j)
      #pragma unroll
      for (int r = 0; r < 4; ++r) {
        int m = m0 + wm + i * 16 + kq * 4 + r;
        int n = n0 + wn + j * 16 + r16;
        float v = acc[i][j][r];
        if (half == 0) v += bias[n];
        out[(size_t)m * kG + n] = v;
      }
}

// ---------------- per-step kernel 2: one batch row per block, 1024 threads ---
__global__ __launch_bounds__(1024, 4) void k_step2(
    float* __restrict__ gx1, const float* __restrict__ gh1,
    const float* __restrict__ gh2,
    float* __restrict__ h1, float* __restrict__ h2,
    unsigned short* __restrict__ h1h, unsigned short* __restrict__ h1l,
    unsigned short* __restrict__ h2h, unsigned short* __restrict__ h2l,
    const unsigned short* __restrict__ whdbT, const float* __restrict__ W_att,
    const unsigned short* __restrict__ fp, const float* __restrict__ c_feats,
    const unsigned short* __restrict__ l1bt, const unsigned short* __restrict__ l2bt,
    const unsigned short* __restrict__ lbt, const unsigned short* __restrict__ iht2b,
    const float* __restrict__ b2_ih,
    const unsigned short* __restrict__ td1bt, const unsigned short* __restrict__ tdbt,
    const unsigned short* __restrict__ iht1b, const float* __restrict__ b1_ih,
    const float* __restrict__ xw,
    unsigned short* __restrict__ h2all_h, unsigned short* __restrict__ h2all_l,
    float* __restrict__ mask_ws, int t) {
  __shared__ float partbuf[8192];     // 32 KB, reused across phases
  __shared__ float h1p[512];
  __shared__ float h2p[512];
  __shared__ float hqs[512];
  __shared__ float scs[256];
  __shared__ float red[16];
  __shared__ float red2[16];
  __shared__ float attl[128];
  __shared__ float lt1[128];
  __shared__ float llv[128];
  __shared__ float s1l[128];
  __shared__ float s2l[128];
  __shared__ float gx2l[1536];
  const int b = blockIdx.x;
  const int tid = threadIdx.x;
  const int lane = tid & 63, wv = tid >> 6;   // 16 waves
  const size_t GPART = (size_t)kB * kG;       // gh k-split partial offset

  // ---- A: GRU1 combine -> h1' ----
  if (tid < 512) {
    int c = tid;
    float gr = gx1[(size_t)b * kG + c];
    float gz = gx1[(size_t)b * kG + 512 + c];
    float gn = gx1[(size_t)b * kG + 1024 + c];
    float hr = gh1[(size_t)b * kG + c] + gh1[GPART + (size_t)b * kG + c];
    float hz = gh1[(size_t)b * kG + 512 + c] + gh1[GPART + (size_t)b * kG + 512 + c];
    float hnv = gh1[(size_t)b * kG + 1024 + c] + gh1[GPART + (size_t)b * kG + 1024 + c];
    float rr = fsigm(gr + hr);
    float zz = fsigm(gz + hz);
    float nn = ftanh(gn + rr * hnv);
    float ho = h1[(size_t)b * kH + c];
    float hn = (1.f - zz) * nn + zz * ho;
    h1[(size_t)b * kH + c] = hn;
    h1p[c] = hn;
    unsigned short hb = f2bf(hn);
    h1h[(size_t)b * kH + c] = hb;
    h1l[(size_t)b * kH + c] = f2bf(hn - bf2f(hb));
  }
  __syncthreads();

  // ---- B: hq = h1' @ W_hidd^T. 64 col-groups(8) x 16 k-groups(32) ----
  {
    int cg = tid & 63, kg = tid >> 6;   // kg 0..15
    int c0 = cg * 8;
    const unsigned short* w = whdbT + (size_t)(kg * 32) * kH + c0;
    float acc[8] = {};
    #pragma unroll 4
    for (int k = 0; k < 32; ++k) {
      union { uint4 u; unsigned short s[8]; } wu;
      wu.u = *(const uint4*)(w + (size_t)k * kH);
      float h = h1p[kg * 32 + k];
      #pragma unroll
      for (int j = 0; j < 8; ++j) acc[j] = fmaf(h, bf2f(wu.s[j]), acc[j]);
    }
    float* pp = &partbuf[kg * 512 + c0];
    #pragma unroll
    for (int j = 0; j < 8; ++j) pp[j] = acc[j];
  }
  __syncthreads();
  if (tid < 512) {
    float s = 0.f;
    #pragma unroll
    for (int g = 0; g < 16; ++g) s += partbuf[g * 512 + tid];
    hqs[tid] = s;
  }
  __syncthreads();

  // ---- C: attention scores (exp-tanh), 16 waves x 16 proposals ----
  {
    float hq8[8], aw[8];
    #pragma unroll
    for (int j = 0; j < 8; ++j) hq8[j] = hqs[lane * 8 + j];
    {
      float4 a0 = *(const float4*)(W_att + lane * 8);
      float4 a1 = *(const float4*)(W_att + lane * 8 + 4);
      aw[0] = a0.x; aw[1] = a0.y; aw[2] = a0.z; aw[3] = a0.w;
      aw[4] = a1.x; aw[5] = a1.y; aw[6] = a1.z; aw[7] = a1.w;
    }
    const unsigned short* fpb = fp + (size_t)b * kP * kH;
    int p0 = wv * 16;
    uint4 rv = *(const uint4*)(fpb + (size_t)p0 * kH + lane * 8);
    for (int p = p0; p < p0 + 16; ++p) {
      union { uint4 v; unsigned short s[8]; } u; u.v = rv;
      if (p + 1 < p0 + 16)
        rv = *(const uint4*)(fpb + (size_t)(p + 1) * kH + lane * 8);
      float sc = 0.f;
      #pragma unroll
      for (int j = 0; j < 8; ++j) {
        float f = __uint_as_float((unsigned)u.s[j] << 16);
        sc += aw[j] * ftanh(f + hq8[j]);
      }
      #pragma unroll
      for (int m = 32; m; m >>= 1) sc += __shfl_xor(sc, m, 64);
      if (lane == 0) scs[p] = sc;
    }
  }
  __syncthreads();

  // ---- D: softmax over 256 proposals ----
  {
    float sv = (tid < 256) ? scs[tid] : -1e30f;
    float mx = sv;
    #pragma unroll
    for (int m = 32; m; m >>= 1) mx = fmaxf(mx, __shfl_xor(mx, m, 64));
    if (lane == 0) red[wv] = mx;
    __syncthreads();
    float bm = red[0];
    #pragma unroll
    for (int i = 1; i < 16; ++i) bm = fmaxf(bm, red[i]);
    float ev = (tid < 256) ? fexp2((sv - bm) * 1.4426950408889634f) : 0.f;
    float sm = ev;
    #pragma unroll
    for (int m = 32; m; m >>= 1) sm += __shfl_xor(sm, m, 64);
    if (lane == 0) red2[wv] = sm;
    __syncthreads();
    float tot = 0.f;
    #pragma unroll
    for (int i = 0; i < 16; ++i) tot += red2[i];
    if (tid < 256) {
      float mk = ev * frcp(tot);
      scs[tid] = mk;
      mask_ws[(size_t)t * (kB * kP) + (size_t)b * kP + tid] = mk;
    }
  }
  __syncthreads();

  // ---- E: attended = mask @ c_feats, 8 proposal-groups x 32 ----
  {
    int c = tid & 127, q = tid >> 7;
    const float* cf = c_feats + ((size_t)b * kP + q * 32) * kC + c;
    const float* ms = scs + q * 32;
    float acc = 0.f;
    for (int p = 0; p < 32; ++p) acc = fmaf(ms[p], cf[(size_t)p * kC], acc);
    partbuf[q * 128 + c] = acc;
  }
  __syncthreads();
  if (tid < 128) {
    float s = 0.f;
    #pragma unroll
    for (int q = 0; q < 8; ++q) s += partbuf[q * 128 + tid];
    attl[tid] = s;
  }
  __syncthreads();

  // ---- F: lt1 = tanh(att@W_l1^T + h1'@W_l2^T) ----
  {
    if (tid < 512) {
      int cg = tid & 15, kg = tid >> 4;
      int c0 = cg * 8;
      const unsigned short* w = l2bt + (size_t)(kg * 16) * kC + c0;
      float acc[8] = {};
      for (int k = 0; k < 16; ++k) {
        union { uint4 u; unsigned short s[8]; } wu;
        wu.u = *(const uint4*)(w + (size_t)k * kC);
        float h = h1p[kg * 16 + k];
        #pragma unroll
        for (int j = 0; j < 8; ++j) acc[j] = fmaf(h, bf2f(wu.s[j]), acc[j]);
      }
      float* pp = &partbuf[kg * 128 + c0];
      #pragma unroll
      for (int j = 0; j < 8; ++j) pp[j] = acc[j];
    } else if (tid < 768) {
      int tt = tid - 512;
      int cg = tt & 15, kg = tt >> 4;
      int c0 = cg * 8;
      const unsigned short* w = l1bt + (size_t)(kg * 8) * kC + c0;
      float acc[8] = {};
      for (int k = 0; k < 8; ++k) {
        union { uint4 u; unsigned short s[8]; } wu;
        wu.u = *(const uint4*)(w + (size_t)k * kC);
        float a = attl[kg * 8 + k];
        #pragma unroll
        for (int j = 0; j < 8; ++j) acc[j] = fmaf(a, bf2f(wu.s[j]), acc[j]);
      }
      float* pp = &partbuf[4096 + kg * 128 + c0];
      #pragma unroll
      for (int j = 0; j < 8; ++j) pp[j] = acc[j];
    }
  }
  __syncthreads();
  if (tid < 128) {
    float s = 0.f;
    #pragma unroll
    for (int g = 0; g < 32; ++g) s += partbuf[g * 128 + tid];
    #pragma unroll
    for (int g = 0; g < 16; ++g) s += partbuf[4096 + g * 128 + tid];
    lt1[tid] = ftanh(s);
  }
  __syncthreads();

  // ---- G: llv = relu(lt1 @ W_l^T), 16 cg x 16 kg (k=8) ----
  if (tid < 256) {
    int cg = tid & 15, kg = tid >> 4;
    int c0 = cg * 8;
    const unsigned short* w = lbt + (size_t)(kg * 8) * kC + c0;
    float acc[8] = {};
    for (int k = 0; k < 8; ++k) {
      union { uint4 u; unsigned short s[8]; } wu;
      wu.u = *(const uint4*)(w + (size_t)k * kC);
      float l = lt1[kg * 8 + k];
      #pragma unroll
      for (int j = 0; j < 8; ++j) acc[j] = fmaf(l, bf2f(wu.s[j]), acc[j]);
    }
    float* pp = &partbuf[kg * 128 + c0];
    #pragma unroll
    for (int j = 0; j < 8; ++j) pp[j] = acc[j];
  }
  __syncthreads();
  if (tid < 128) {
    float s = 0.f;
    #pragma unroll
    for (int g = 0; g < 16; ++g) s += partbuf[g * 128 + tid];
    llv[tid] = fmaxf(s, 0.f);
  }
  __syncthreads();

  // ---- H: gx2 = llv @ W2_ih^T + b2. 192 cg(8) x 4 kg(32) ----
  if (tid < 768) {
    int cg = tid % 192, kg = tid / 192;
    int c0 = cg * 8;
    const unsigned short* w = iht2b + (size_t)(kg * 32) * kG + c0;
    float acc[8] = {};
    #pragma unroll 4
    for (int k = 0; k < 32; ++k) {
      union { uint4 u; unsigned short s[8]; } wu;
      wu.u = *(const uint4*)(w + (size_t)k * kG);
      float l = llv[kg * 32 + k];
      #pragma unroll
      for (int j = 0; j < 8; ++j) acc[j] = fmaf(l, bf2f(wu.s[j]), acc[j]);
    }
    float* pp = &partbuf[kg * 1536 + c0];
    #pragma unroll
    for (int j = 0; j < 8; ++j) pp[j] = acc[j];
  }
  __syncthreads();
  for (int c = tid; c < kG; c += 1024) {
    float s = b2_ih[c];
    #pragma unroll
    for (int g = 0; g < 4; ++g) s += partbuf[g * 1536 + c];
    gx2l[c] = s;
  }
  __syncthreads();
  if (tid < 512) {
    int c = tid;
    float ghr = gh2[(size_t)b * kG + c] + gh2[GPART + (size_t)b * kG + c];
    float ghz = gh2[(size_t)b * kG + 512 + c] + gh2[GPART + (size_t)b * kG + 512 + c];
    float ghn = gh2[(size_t)b * kG + 1024 + c] + gh2[GPART + (size_t)b * kG + 1024 + c];
    float rr = fsigm(gx2l[c] + ghr);
    float zz = fsigm(gx2l[512 + c] + ghz);
    float nn = ftanh(gx2l[1024 + c] + rr * ghn);
    float ho = h2[(size_t)b * kH + c];
    float hn = (1.f - zz) * nn + zz * ho;
    h2[(size_t)b * kH + c] = hn;
    h2p[c] = hn;
    unsigned short hb = f2bf(hn);
    unsigned short lb = f2bf(hn - bf2f(hb));
    h2h[(size_t)b * kH + c] = hb;
    h2l[(size_t)b * kH + c] = lb;
    size_t o = ((size_t)t * kB + b) * kH + c;
    h2all_h[o] = hb;
    h2all_l[o] = lb;
  }
  __syncthreads();

  // ---- I: next step's s-chain + gx1 ----
  if (t + 1 < kNS) {
    // I1: s1 = tanh(xw[t+1] + h2'@W_td1^T), 16 cg x 32 kg (k=16)
    if (tid < 512) {
      int cg = tid & 15, kg = tid >> 4;
      int c0 = cg * 8;
      const unsigned short* w = td1bt + (size_t)(kg * 16) * kC + c0;
      float acc[8] = {};
      for (int k = 0; k < 16; ++k) {
        union { uint4 u; unsigned short s[8]; } wu;
        wu.u = *(const uint4*)(w + (size_t)k * kC);
        float h = h2p[kg * 16 + k];
        #pragma unroll
        for (int j = 0; j < 8; ++j) acc[j] = fmaf(h, bf2f(wu.s[j]), acc[j]);
      }
      float* pp = &partbuf[kg * 128 + c0];
      #pragma unroll
      for (int j = 0; j < 8; ++j) pp[j] = acc[j];
    }
    __syncthreads();
    if (tid < 128) {
      float s = xw[((size_t)(t + 1) * kB + b) * kC + tid];
      #pragma unroll
      for (int g = 0; g < 32; ++g) s += partbuf[g * 128 + tid];
      s1l[tid] = ftanh(s);
    }
    __syncthreads();
    // I2: s2 = relu(s1 @ W_td^T), 16 cg x 16 kg (k=8)
    if (tid < 256) {
      int cg = tid & 15, kg = tid >> 4;
      int c0 = cg * 8;
      const unsigned short* w = tdbt + (size_t)(kg * 8) * kC + c0;
      float acc[8] = {};
      for (int k = 0; k < 8; ++k) {
        union { uint4 u; unsigned short s[8]; } wu;
        wu.u = *(const uint4*)(w + (size_t)k * kC);
        float sv = s1l[kg * 8 + k];
        #pragma unroll
        for (int j = 0; j < 8; ++j) acc[j] = fmaf(sv, bf2f(wu.s[j]), acc[j]);
      }
      float* pp = &partbuf[kg * 128 + c0];
      #pragma unroll
      for (int j = 0; j < 8; ++j) pp[j] = acc[j];
    }
    __syncthreads();
    if (tid < 128) {
      float s = 0.f;
      #pragma unroll
      for (int g = 0; g < 16; ++g) s += partbuf[g * 128 + tid];
      s2l[tid] = fmaxf(s, 0.f);
    }
    __syncthreads();
    // I3: gx1(t+1) = s2 @ W1_ih^T + b1. 192 cg(8) x 4 kg(32)
    if (tid < 768) {
      int cg = tid % 192, kg = tid / 192;
      int c0 = cg * 8;
      const unsigned short* w = iht1b + (size_t)(kg * 32) * kG + c0;
      float acc[8] = {};
      #pragma unroll 4
      for (int k = 0; k < 32; ++k) {
        union { uint4 u; unsigned short s[8]; } wu;
        wu.u = *(const uint4*)(w + (size_t)k * kG);
        float sv = s2l[kg * 32 + k];
        #pragma unroll
        for (int j = 0; j < 8; ++j) acc[j] = fmaf(sv, bf2f(wu.s[j]), acc[j]);
      }
      float* pp = &partbuf[kg * 1536 + c0];
      #pragma unroll
      for (int j = 0; j < 8; ++j) pp[j] = acc[j];
    }
    __syncthreads();
    for (int c = tid; c < kG; c += 1024) {
      float s = b1_ih[c];
      #pragma unroll
      for (int g = 0; g < 4; ++g) s += partbuf[g * 1536 + c];
      gx1[(size_t)b * kG + c] = s;
    }
  }
}

// ---------------- mask transpose via LDS: [t][b][p] -> out[b][p][t] ----------
__global__ __launch_bounds__(256) void k_atrans(
    const float* __restrict__ mws, float* __restrict__ attn_out) {
  __shared__ float tile[256][33];
  int pair0 = blockIdx.x * 256;     // 256 blocks cover 65536 (b,p) pairs
  int tid = threadIdx.x;
  #pragma unroll
  for (int t = 0; t < kNS; ++t)
    tile[tid][t] = mws[(size_t)t * (kB * kP) + pair0 + tid];
  __syncthreads();
  float* outb = attn_out + (size_t)pair0 * kNS;
  #pragma unroll
  for (int i = 0; i < kNS; ++i) {
    int g = i * 256 + tid;           // 0..7935 contiguous output floats
    int pr = g / 31, tt = g - pr * 31;
    outb[g] = tile[pr][tt];
  }
}

// ---------------- classifier: lang = h2_all @ W_cls^T + b_cls (MFMA, LDS) ----
__global__ __launch_bounds__(256) void k_cls(
    const unsigned short* __restrict__ Ah, const unsigned short* __restrict__ Al,
    const unsigned short* __restrict__ Wh,
    const float* __restrict__ bc, float* __restrict__ out) {
  __shared__ __align__(16) unsigned short sAh[4096], sAl[4096], sBh[4096];
  int m0 = blockIdx.x * 128, n0 = blockIdx.y * 128;
  f32x4 acc[4][4];
  #pragma unroll
  for (int i = 0; i < 4; ++i)
    #pragma unroll
    for (int j = 0; j < 4; ++j) acc[i][j] = (f32x4){0.f, 0.f, 0.f, 0.f};
  mm_tile_lds(Ah, Al, Wh, m0, n0, kH, 0, kH, kV - 1, acc, sAh, sAl, sBh);
  int lane = threadIdx.x & 63, wid = threadIdx.x >> 6;
  int wm = (wid >> 1) * 64, wn = (wid & 1) * 64;
  int r16 = lane & 15, kq = lane >> 4;
  #pragma unroll
  for (int i = 0; i < 4; ++i)
    #pragma unroll
    for (int j = 0; j < 4; ++j)
      #pragma unroll
      for (int r = 0; r < 4; ++r) {
        int m = m0 + wm + i * 16 + kq * 4 + r;
        int n = n0 + wn + j * 16 + r16;
        if (n < kV) {
          int tt = m >> 8, b = m & 255;
          out[(size_t)b * (kNS * kV) + (size_t)tt * kV + n] = acc[i][j][r] + bc[n];
        }
      }
}

}  // namespace

extern "C" void kernel_launch(void* const* d_in, const int* in_sizes, int n_in,
                              void* d_out, int out_size, void* d_ws,
                              size_t ws_size, hipStream_t stream) {
  (void)in_sizes; (void)n_in; (void)out_size; (void)ws_size;
  const float* word_embs = (const float*)d_in[0];
  const float* t_feat    = (const float*)d_in[1];
  const float* c_feats   = (const float*)d_in[2];
  const float* W_td1 = (const float*)d_in[4];
  const float* W_td2 = (const float*)d_in[5];
  const float* W_td3 = (const float*)d_in[6];
  const float* W_td  = (const float*)d_in[7];
  const float* W1_ih = (const float*)d_in[8];
  const float* W1_hh = (const float*)d_in[9];
  const float* b1_ih = (const float*)d_in[10];
  const float* b1_hh = (const float*)d_in[11];
  const float* W_feat = (const float*)d_in[12];
  const float* W_hidd = (const float*)d_in[13];
  const float* W_att  = (const float*)d_in[14];
  const float* W_l1 = (const float*)d_in[15];
  const float* W_l2 = (const float*)d_in[16];
  const float* W_l  = (const float*)d_in[17];
  const float* W2_ih = (const float*)d_in[18];
  const float* W2_hh = (const float*)d_in[19];
  const float* b2_ih = (const float*)d_in[20];
  const float* b2_hh = (const float*)d_in[21];
  const float* W_cls = (const float*)d_in[22];
  const float* b_cls = (const float*)d_in[23];

  float* lang = (float*)d_out;
  float* attn_out = lang + (size_t)kB * kNS * kV;
  // feat_proj (bf16, 64MB) lives in the lang_cap region of d_out — dead by
  // the time k_cls (the only writer of lang_cap) runs.
  unsigned short* fp = (unsigned short*)d_out;

  float* p = (float*)d_ws;
  float* h1 = p;      p += kB * kH;
  float* h2 = p;      p += kB * kH;
  float* td = p;      p += kB * kC;
  float* gx1 = p;     p += (size_t)kB * kG;
  float* gh1 = p;     p += (size_t)2 * kB * kG;   // 2 K-split partials
  float* gh2 = p;     p += (size_t)2 * kB * kG;
  float* mask_ws = p; p += (size_t)kNS * kB * kP;
  float* xw = p;      p += (size_t)kNS * kB * kC;
  float* td3t = p;    p += kE * 128;
  float* td1t = p;    p += kH * 128;
  float* tdt  = p;    p += 128 * 128;
  float* l1t  = p;    p += 128 * 128;
  float* l2t  = p;    p += kH * 128;
  float* lt   = p;    p += 128 * 128;
  float* iht1 = p;    p += 128 * kG;
  float* iht2 = p;    p += 128 * kG;
  float* whd_t = p;   p += kH * kH;

  unsigned short* u = (unsigned short*)p;
  unsigned short* h1h = u;     u += kB * kH;
  unsigned short* h1l = u;     u += kB * kH;
  unsigned short* h2h = u;     u += kB * kH;
  unsigned short* h2l = u;     u += kB * kH;
  unsigned short* w1hh_h = u;  u += (size_t)kG * kH;
  unsigned short* w1hh_l = u;  u += (size_t)kG * kH;
  unsigned short* w2hh_h = u;  u += (size_t)kG * kH;
  unsigned short* w2hh_l = u;  u += (size_t)kG * kH;
  unsigned short* wc_h = u;    u += (size_t)kV * kH;
  unsigned short* wc_l = u;    u += (size_t)kV * kH;
  unsigned short* wf_h = u;    u += (size_t)kH * kC;
  unsigned short* wf_l = u;    u += (size_t)kH * kC;
  unsigned short* h2all_h = u; u += (size_t)kNS * kB * kH;
  unsigned short* h2all_l = u; u += (size_t)kNS * kB * kH;
  unsigned short* l1bt = u;    u += kC * kC;
  unsigned short* l2bt = u;    u += (size_t)kH * kC;
  unsigned short* lbt = u;     u += kC * kC;
  unsigned short* iht2b = u;   u += (size_t)kC * kG;
  unsigned short* whdbT = u;   u += (size_t)kH * kH;
  unsigned short* td1bt = u;   u += (size_t)kH * kC;
  unsigned short* tdbt = u;    u += kC * kC;
  unsigned short* iht1b = u;   u += (size_t)kC * kG;

  k_transpose<<<dim3(64, 9), 256, 0, stream>>>(
      W_td3, W_td1, W_td, W_l1, W_l2, W_l, W1_ih, W2_ih, W_hidd,
      td3t, td1t, tdt, l1t, l2t, lt, iht1, iht2, whd_t);
  k_tobf16<<<dim3(96, 8), 256, 0, stream>>>(
      l1t, l2t, lt, iht2, whd_t, td1t, tdt, iht1,
      l1bt, l2bt, lbt, iht2b, whdbT, td1bt, tdbt, iht1b);
  k_split<<<dim3(256, 4), 256, 0, stream>>>(
      W1_hh, W2_hh, W_cls, W_feat,
      w1hh_h, w1hh_l, w2hh_h, w2hh_l, wc_h, wc_l, wf_h, wf_l);
  k_init<<<128, 256, 0, stream>>>(t_feat, W_td2, td, h1, h2,
                                  h1h, h1l, h2h, h2l);
  k_featproj<<<dim3(512, 4), 256, 0, stream>>>(c_feats, wf_h, fp);
  k_xw<<<dim3(64, kNS), 256, 0, stream>>>(word_embs, td3t, td, xw);
  k_prestep<<<256, 256, 0, stream>>>(xw, tdbt, iht1b, b1_ih, gx1);

  for (int t = 0; t < kNS; ++t) {
    k_gh<<<96, 256, 0, stream>>>(h1h, h1l, h2h, h2l,
                                 w1hh_h, w2hh_h, b1_hh, b2_hh, gh1, gh2);
    k_step2<<<256, 1024, 0, stream>>>(gx1, gh1, gh2, h1, h2,
                                      h1h, h1l, h2h, h2l, whdbT, W_att, fp,
                                      c_feats, l1bt, l2bt, lbt, iht2b, b2_ih,
                                      td1bt, tdbt, iht1b, b1_ih, xw,
                                      h2all_h, h2all_l, mask_ws, t);
  }
  k_atrans<<<256, 256, 0, stream>>>(mask_ws, attn_out);
  k_cls<<<dim3(62, 27), 256, 0, stream>>>(h2all_h, h2all_l, wc_h,
                                          b_cls, lang);
}

// Round 13
// 1915.430 us; speedup vs baseline: 1.2839x; 1.1042x over previous
//
#include <hip/hip_runtime.h>
#include <hip/hip_bf16.h>

namespace {

constexpr int kB  = 256;   // batch
constexpr int kP  = 256;   // proposals
constexpr int kT  = 32;    // words
constexpr int kNS = 31;    // steps = T-1
constexpr int kV  = 3433;  // vocab
constexpr int kH  = 512;   // hidden
constexpr int kE  = 300;   // embed
constexpr int kC  = 128;   // feat dim
constexpr int kG  = 1536;  // 3H

typedef __bf16 bf16x8 __attribute__((ext_vector_type(8)));
typedef float f32x4 __attribute__((ext_vector_type(4)));

__device__ __forceinline__ float fexp2(float x) {
  float r; asm("v_exp_f32 %0, %1" : "=v"(r) : "v"(x)); return r;
}
__device__ __forceinline__ float frcp(float x) {
  float r; asm("v_rcp_f32 %0, %1" : "=v"(r) : "v"(x)); return r;
}
__device__ __forceinline__ float ftanh(float x) {
  float e = fexp2(x * 2.8853900817779268f);   // e^(2x)
  return 1.0f - 2.0f * frcp(e + 1.0f);
}
__device__ __forceinline__ float fsigm(float x) {
  return frcp(1.0f + fexp2(x * -1.4426950408889634f));
}
__device__ __forceinline__ unsigned short f2bf(float f) {   // RNE bf16
  unsigned u = __float_as_uint(f);
  u += 0x7FFFu + ((u >> 16) & 1u);
  return (unsigned short)(u >> 16);
}
__device__ __forceinline__ float bf2f(unsigned short s) {
  return __uint_as_float((unsigned)s << 16);
}

// ---------------- one-time weight transposes (W[r][k] -> Wt[k*R + r]) -------
__global__ void k_transpose(const float* s0, const float* s1, const float* s2,
                            const float* s3, const float* s4, const float* s5,
                            const float* s6, const float* s7, const float* s8,
                            float* d0, float* d1, float* d2, float* d3,
                            float* d4, float* d5, float* d6, float* d7,
                            float* d8) {
  const float* src; float* dst; int R, Cd;
  switch (blockIdx.y) {
    case 0:  src = s0; dst = d0; R = 128;  Cd = 300; break;  // W_td3
    case 1:  src = s1; dst = d1; R = 128;  Cd = 512; break;  // W_td1
    case 2:  src = s2; dst = d2; R = 128;  Cd = 128; break;  // W_td
    case 3:  src = s3; dst = d3; R = 128;  Cd = 128; break;  // W_l1
    case 4:  src = s4; dst = d4; R = 128;  Cd = 512; break;  // W_l2
    case 5:  src = s5; dst = d5; R = 128;  Cd = 128; break;  // W_l
    case 6:  src = s6; dst = d6; R = 1536; Cd = 128; break;  // W1_ih
    case 7:  src = s7; dst = d7; R = 1536; Cd = 128; break;  // W2_ih
    default: src = s8; dst = d8; R = 512;  Cd = 512; break;  // W_hidd
  }
  int n = R * Cd;
  for (int i = blockIdx.x * blockDim.x + threadIdx.x; i < n;
       i += gridDim.x * blockDim.x) {
    int k = i / R, r = i - k * R;
    dst[i] = src[r * Cd + k];    // dst[k*R + r]
  }
}

// ---------------- bf16 copies of the loop-local weights ----------------------
__global__ void k_tobf16(const float* s0, const float* s1, const float* s2,
                         const float* s3, const float* s4, const float* s5,
                         const float* s6, const float* s7,
                         unsigned short* d0, unsigned short* d1,
                         unsigned short* d2, unsigned short* d3,
                         unsigned short* d4, unsigned short* d5,
                         unsigned short* d6, unsigned short* d7) {
  const float* s; unsigned short* d; int n;
  switch (blockIdx.y) {
    case 0:  s = s0; d = d0; n = kC * kC; break;   // l1t
    case 1:  s = s1; d = d1; n = kH * kC; break;   // l2t
    case 2:  s = s2; d = d2; n = kC * kC; break;   // lt
    case 3:  s = s3; d = d3; n = kC * kG; break;   // iht2
    case 4:  s = s4; d = d4; n = kH * kH; break;   // whd_t
    case 5:  s = s5; d = d5; n = kH * kC; break;   // td1t
    case 6:  s = s6; d = d6; n = kC * kC; break;   // tdt
    default: s = s7; d = d7; n = kG * kC; break;   // W1_ih (row-major!)
  }
  for (int i = blockIdx.x * blockDim.x + threadIdx.x; i < n;
       i += gridDim.x * blockDim.x)
    d[i] = f2bf(s[i]);
}

// ---------------- one-time weight hi/lo bf16 splits --------------------------
__global__ void k_split(const float* s0, const float* s1, const float* s2,
                        const float* s3,
                        unsigned short* h0, unsigned short* l0,
                        unsigned short* h1, unsigned short* l1,
                        unsigned short* h2, unsigned short* l2,
                        unsigned short* h3, unsigned short* l3) {
  const float* s; unsigned short* h; unsigned short* l; int n;
  switch (blockIdx.y) {
    case 0:  s = s0; h = h0; l = l0; n = kG * kH; break;   // W1_hh
    case 1:  s = s1; h = h1; l = l1; n = kG * kH; break;   // W2_hh
    case 2:  s = s2; h = h2; l = l2; n = kV * kH; break;   // W_cls
    default: s = s3; h = h3; l = l3; n = kH * kC; break;   // W_feat
  }
  for (int i = blockIdx.x * blockDim.x + threadIdx.x; i < n;
       i += gridDim.x * blockDim.x) {
    float v = s[i];
    unsigned short hb = f2bf(v);
    h[i] = hb;
    l[i] = f2bf(v - bf2f(hb));
  }
}

// ---------------- init: td = t_feat @ W_td2^T ; zero h states ----------------
__global__ void k_init(const float* __restrict__ t_feat,
                       const float* __restrict__ W_td2,
                       float* __restrict__ td, float* __restrict__ h1,
                       float* __restrict__ h2,
                       unsigned short* __restrict__ h1h,
                       unsigned short* __restrict__ h1l,
                       unsigned short* __restrict__ h2h,
                       unsigned short* __restrict__ h2l) {
  int tid = blockIdx.x * 256 + threadIdx.x;  // 32768 threads
  int b = tid >> 7, c = tid & 127;
  const float* tf = t_feat + b * kC;
  const float* w  = W_td2 + c * kC;
  float acc = 0.f;
  for (int k = 0; k < kC; ++k) acc = fmaf(tf[k], w[k], acc);
  td[tid] = acc;
  for (int i = tid; i < kB * kH; i += (1 << 15)) {
    h1[i] = 0.f; h2[i] = 0.f;
    h1h[i] = 0; h1l[i] = 0; h2h[i] = 0; h2l[i] = 0;
  }
}

// ---------------- xw[t][b][:] = x_t @ W_td3^T + td ---------------------------
__global__ __launch_bounds__(256) void k_xw(
    const float* __restrict__ word_embs, const float* __restrict__ td3t,
    const float* __restrict__ td, float* __restrict__ xw) {
  __shared__ float xl[4 * 300];
  __shared__ float tdl[512];
  int t = blockIdx.y, b0 = blockIdx.x * 4, tid = threadIdx.x;
  #pragma unroll
  for (int r = 0; r < 4; ++r) {
    const float* xs = word_embs + (size_t)(b0 + r) * (kT * kE) + (size_t)t * kE;
    for (int e = tid; e < kE; e += 256) xl[r * kE + e] = xs[e];
  }
  for (int i = tid; i < 512; i += 256) tdl[i] = td[(size_t)b0 * kC + i];
  __syncthreads();
  #pragma unroll
  for (int q = 0; q < 2; ++q) {
    int idx = tid + q * 256;
    int r = idx >> 7, c = idx & 127;
    float acc = tdl[idx];
    const float* xr = xl + r * kE;
    const float* w3 = td3t + c;
    for (int e = 0; e < kE; ++e) acc = fmaf(xr[e], w3[(size_t)e * 128], acc);
    xw[((size_t)t * kB + b0 + r) * kC + c] = acc;
  }
}

// ---------------- prestep: s2(t=0) hi/lo from xw[0] (h2 = 0) -----------------
__global__ __launch_bounds__(256) void k_prestep(
    const float* __restrict__ xw, const unsigned short* __restrict__ tdbt,
    unsigned short* __restrict__ s2h, unsigned short* __restrict__ s2l) {
  __shared__ float s1l[128];
  __shared__ float part[256];
  int b = blockIdx.x, tid = threadIdx.x;
  if (tid < 128) s1l[tid] = ftanh(xw[(size_t)b * kC + tid]);
  __syncthreads();
  {
    int c = tid & 127, g = tid >> 7;
    float s = 0.f;
    const unsigned short* w = tdbt + (size_t)(g * 64) * kC + c;
    for (int k = 0; k < 64; ++k)
      s = fmaf(s1l[g * 64 + k], bf2f(w[(size_t)k * kC]), s);
    part[g * 128 + c] = s;
  }
  __syncthreads();
  if (tid < 128) {
    float s = fmaxf(part[tid] + part[128 + tid], 0.f);
    unsigned short hb = f2bf(s);
    s2h[(size_t)b * kC + tid] = hb;
    s2l[(size_t)b * kC + tid] = f2bf(s - bf2f(hb));
  }
}

// ---------------- LDS-staged split-bf16 MFMA 128x128 tile (2-term) -----------
// C = (Ahi+Alo) * Bhi. 256 threads. Prefetch-pipelined: global loads for
// k+1 issue before the MFMA cluster of k, hiding L2/HBM latency under
// compute. 16B slot XOR-swizzled by (row>>1)&3 -> zero bank conflicts.
__device__ __forceinline__ void mm_tile_lds(
    const unsigned short* __restrict__ Ah, const unsigned short* __restrict__ Al,
    const unsigned short* __restrict__ Bh,
    int m0, int n0, int K, int kbeg, int kend, int nMax, f32x4 acc[4][4],
    unsigned short* sAh, unsigned short* sAl, unsigned short* sBh) {
  int tid = threadIdx.x;
  int lane = tid & 63, wid = tid >> 6;
  int wm = (wid >> 1) * 64, wn = (wid & 1) * 64;
  int r16 = lane & 15, kq = lane >> 4;
  int rA = tid >> 2;
  int swSlot = (((tid & 3) ^ ((rA >> 1) & 3)) * 8);   // write-side swizzle
  int cA = (tid & 3) * 8;                             // global k-chunk
  int swr = (kq ^ ((r16 >> 1) & 3)) * 8;              // read-side swizzle
  int brow0 = n0 + rA;       if (brow0 > nMax) brow0 = nMax;
  int brow1 = n0 + rA + 64;  if (brow1 > nMax) brow1 = nMax;
  const unsigned short* pa0 = Ah + (size_t)(m0 + rA) * K + cA;
  const unsigned short* pa1 = Ah + (size_t)(m0 + rA + 64) * K + cA;
  const unsigned short* pb0 = Al + (size_t)(m0 + rA) * K + cA;
  const unsigned short* pb1 = Al + (size_t)(m0 + rA + 64) * K + cA;
  const unsigned short* pc0 = Bh + (size_t)brow0 * K + cA;
  const unsigned short* pc1 = Bh + (size_t)brow1 * K + cA;
  uint4 va0 = *(const uint4*)(pa0 + kbeg);
  uint4 va1 = *(const uint4*)(pa1 + kbeg);
  uint4 vb0 = *(const uint4*)(pb0 + kbeg);
  uint4 vb1 = *(const uint4*)(pb1 + kbeg);
  uint4 vc0 = *(const uint4*)(pc0 + kbeg);
  uint4 vc1 = *(const uint4*)(pc1 + kbeg);
  for (int k0 = kbeg; k0 < kend; k0 += 32) {
    __syncthreads();   // previous chunk's reads complete
    *(uint4*)&sAh[rA * 32 + swSlot] = va0;
    *(uint4*)&sAh[(rA + 64) * 32 + swSlot] = va1;
    *(uint4*)&sAl[rA * 32 + swSlot] = vb0;
    *(uint4*)&sAl[(rA + 64) * 32 + swSlot] = vb1;
    *(uint4*)&sBh[rA * 32 + swSlot] = vc0;
    *(uint4*)&sBh[(rA + 64) * 32 + swSlot] = vc1;
    __syncthreads();
    if (k0 + 32 < kend) {          // prefetch next chunk under the MFMAs
      int kn = k0 + 32;
      va0 = *(const uint4*)(pa0 + kn);
      va1 = *(const uint4*)(pa1 + kn);
      vb0 = *(const uint4*)(pb0 + kn);
      vb1 = *(const uint4*)(pb1 + kn);
      vc0 = *(const uint4*)(pc0 + kn);
      vc1 = *(const uint4*)(pc1 + kn);
    }
    bf16x8 ah[4], al[4], bh[4];
    #pragma unroll
    for (int i = 0; i < 4; ++i) {
      int ar = (wm + i * 16 + r16) * 32 + swr;
      int br = (wn + i * 16 + r16) * 32 + swr;
      ah[i] = *(const bf16x8*)&sAh[ar];
      al[i] = *(const bf16x8*)&sAl[ar];
      bh[i] = *(const bf16x8*)&sBh[br];
    }
    #pragma unroll
    for (int i = 0; i < 4; ++i)
      #pragma unroll
      for (int j = 0; j < 4; ++j) {
        acc[i][j] = __builtin_amdgcn_mfma_f32_16x16x32_bf16(ah[i], bh[j], acc[i][j], 0, 0, 0);
        acc[i][j] = __builtin_amdgcn_mfma_f32_16x16x32_bf16(al[i], bh[j], acc[i][j], 0, 0, 0);
      }
  }
}

// ---------------- feat_proj = c_feats @ W_feat^T -> bf16 (MFMA, 2-term) ------
__global__ __launch_bounds__(256) void k_featproj(
    const float* __restrict__ A, const unsigned short* __restrict__ Wh,
    unsigned short* __restrict__ out) {
  int lane = threadIdx.x & 63, wid = threadIdx.x >> 6;
  int wm = (wid >> 1) * 64, wn = (wid & 1) * 64;
  int r16 = lane & 15, kq = lane >> 4;
  int m0 = blockIdx.x * 128, n0 = blockIdx.y * 128;
  f32x4 acc[4][4];
  #pragma unroll
  for (int i = 0; i < 4; ++i)
    #pragma unroll
    for (int j = 0; j < 4; ++j) acc[i][j] = (f32x4){0.f, 0.f, 0.f, 0.f};
  for (int k0 = 0; k0 < kC; k0 += 32) {
    int kk = k0 + kq * 8;
    bf16x8 ah[4], al[4], bh[4];
    #pragma unroll
    for (int i = 0; i < 4; ++i) {
      const float* pa = A + (size_t)(m0 + wm + i * 16 + r16) * kC + kk;
      float4 v0 = *(const float4*)pa;
      float4 v1 = *(const float4*)(pa + 4);
      float vv[8] = {v0.x, v0.y, v0.z, v0.w, v1.x, v1.y, v1.z, v1.w};
      union { unsigned short s[8]; bf16x8 v; } uh, ul;
      #pragma unroll
      for (int q = 0; q < 8; ++q) {
        unsigned short hb = f2bf(vv[q]);
        uh.s[q] = hb;
        ul.s[q] = f2bf(vv[q] - bf2f(hb));
      }
      ah[i] = uh.v; al[i] = ul.v;
      const unsigned short* pb = Wh + (size_t)(n0 + wn + i * 16 + r16) * kC + kk;
      union { uint4 u; bf16x8 v; } xb;
      xb.u = *(const uint4*)pb;
      bh[i] = xb.v;
    }
    #pragma unroll
    for (int i = 0; i < 4; ++i)
      #pragma unroll
      for (int j = 0; j < 4; ++j) {
        acc[i][j] = __builtin_amdgcn_mfma_f32_16x16x32_bf16(ah[i], bh[j], acc[i][j], 0, 0, 0);
        acc[i][j] = __builtin_amdgcn_mfma_f32_16x16x32_bf16(al[i], bh[j], acc[i][j], 0, 0, 0);
      }
  }
  #pragma unroll
  for (int i = 0; i < 4; ++i)
    #pragma unroll
    for (int j = 0; j < 4; ++j)
      #pragma unroll
      for (int r = 0; r < 4; ++r) {
        int m = m0 + wm + i * 16 + kq * 4 + r;
        int n = n0 + wn + j * 16 + r16;
        out[(size_t)m * kH + n] = f2bf(acc[i][j][r]);
      }
}

// ---------------- per-step kernel 1 (120 blocks) ------------------------------
// Blocks 0..95:  gh1/gh2 MFMA, K-split x2 (partials; bias in half 0).
// Blocks 96..119: gx1 = s2 @ W1_ih^T + b1_ih (MFMA, K=128, 2x12 tiles).
__global__ __launch_bounds__(256) void k_gh(
    const unsigned short* __restrict__ h1h, const unsigned short* __restrict__ h1l,
    const unsigned short* __restrict__ h2h, const unsigned short* __restrict__ h2l,
    const unsigned short* __restrict__ w1hh_h, const unsigned short* __restrict__ w2hh_h,
    const float* __restrict__ b1_hh, const float* __restrict__ b2_hh,
    float* __restrict__ gh1, float* __restrict__ gh2,
    const unsigned short* __restrict__ s2h, const unsigned short* __restrict__ s2l,
    const unsigned short* __restrict__ w1ih_h, const float* __restrict__ b1_ih,
    float* __restrict__ gx1) {
  __shared__ __align__(16) unsigned short sAh[4096], sAl[4096], sBh[4096];
  int blk = blockIdx.x, tid = threadIdx.x;
  int lane = tid & 63, wid = tid >> 6;
  int wm = (wid >> 1) * 64, wn = (wid & 1) * 64;
  int r16 = lane & 15, kq = lane >> 4;
  f32x4 acc[4][4];
  #pragma unroll
  for (int i = 0; i < 4; ++i)
    #pragma unroll
    for (int j = 0; j < 4; ++j) acc[i][j] = (f32x4){0.f, 0.f, 0.f, 0.f};
  if (blk < 96) {
    int half = blk & 1, g = blk >> 1;   // g 0..47
    const unsigned short *Ah, *Al, *Wh; const float* bias; float* out;
    if (g < 24) { Ah = h1h; Al = h1l; Wh = w1hh_h; bias = b1_hh; out = gh1; }
    else { g -= 24; Ah = h2h; Al = h2l; Wh = w2hh_h; bias = b2_hh; out = gh2; }
    out += (size_t)half * (kB * kG);
    int m0 = (g / 12) * 128, n0 = (g % 12) * 128;
    mm_tile_lds(Ah, Al, Wh, m0, n0, kH, half * 256, half * 256 + 256,
                kG - 1, acc, sAh, sAl, sBh);
    #pragma unroll
    for (int i = 0; i < 4; ++i)
      #pragma unroll
      for (int j = 0; j < 4; ++j)
        #pragma unroll
        for (int r = 0; r < 4; ++r) {
          int m = m0 + wm + i * 16 + kq * 4 + r;
          int n = n0 + wn + j * 16 + r16;
          float v = acc[i][j][r];
          if (half == 0) v += bias[n];
          out[(size_t)m * kG + n] = v;
        }
  } else {
    int gg = blk - 96;   // 0..23
    int m0 = (gg / 12) * 128, n0 = (gg % 12) * 128;
    mm_tile_lds(s2h, s2l, w1ih_h, m0, n0, kC, 0, kC, kG - 1, acc,
                sAh, sAl, sBh);
    #pragma unroll
    for (int i = 0; i < 4; ++i)
      #pragma unroll
      for (int j = 0; j < 4; ++j)
        #pragma unroll
        for (int r = 0; r < 4; ++r) {
          int m = m0 + wm + i * 16 + kq * 4 + r;
          int n = n0 + wn + j * 16 + r16;
          gx1[(size_t)m * kG + n] = acc[i][j][r] + b1_ih[n];
        }
  }
}

// ---------------- per-step kernel 2: one batch row per block, 1024 threads ---
__global__ __launch_bounds__(1024, 4) void k_step2(
    const float* __restrict__ gx1, const float* __restrict__ gh1,
    const float* __restrict__ gh2,
    float* __restrict__ h1, float* __restrict__ h2,
    unsigned short* __restrict__ h1h, unsigned short* __restrict__ h1l,
    unsigned short* __restrict__ h2h, unsigned short* __restrict__ h2l,
    const unsigned short* __restrict__ whdbT, const float* __restrict__ W_att,
    const unsigned short* __restrict__ fp, const float* __restrict__ c_feats,
    const unsigned short* __restrict__ l1bt, const unsigned short* __restrict__ l2bt,
    const unsigned short* __restrict__ lbt, const unsigned short* __restrict__ iht2b,
    const float* __restrict__ b2_ih,
    const unsigned short* __restrict__ td1bt, const unsigned short* __restrict__ tdbt,
    const float* __restrict__ xw,
    unsigned short* __restrict__ s2h, unsigned short* __restrict__ s2l,
    unsigned short* __restrict__ h2all_h, unsigned short* __restrict__ h2all_l,
    float* __restrict__ mask_ws, int t) {
  __shared__ float partbuf[8192];     // 32 KB, reused across phases
  __shared__ float h1p[512];
  __shared__ float h2p[512];
  __shared__ float hqs[512];
  __shared__ float scs[256];
  __shared__ float red[16];
  __shared__ float red2[16];
  __shared__ float attl[128];
  __shared__ float lt1[128];
  __shared__ float llv[128];
  __shared__ float s1l[128];
  __shared__ float gx2l[1536];
  const int b = blockIdx.x;
  const int tid = threadIdx.x;
  const int lane = tid & 63, wv = tid >> 6;   // 16 waves
  const size_t GPART = (size_t)kB * kG;       // gh k-split partial offset

  // ---- A: GRU1 combine -> h1' ----
  if (tid < 512) {
    int c = tid;
    float gr = gx1[(size_t)b * kG + c];
    float gz = gx1[(size_t)b * kG + 512 + c];
    float gn = gx1[(size_t)b * kG + 1024 + c];
    float hr = gh1[(size_t)b * kG + c] + gh1[GPART + (size_t)b * kG + c];
    float hz = gh1[(size_t)b * kG + 512 + c] + gh1[GPART + (size_t)b * kG + 512 + c];
    float hnv = gh1[(size_t)b * kG + 1024 + c] + gh1[GPART + (size_t)b * kG + 1024 + c];
    float rr = fsigm(gr + hr);
    float zz = fsigm(gz + hz);
    float nn = ftanh(gn + rr * hnv);
    float ho = h1[(size_t)b * kH + c];
    float hn = (1.f - zz) * nn + zz * ho;
    h1[(size_t)b * kH + c] = hn;
    h1p[c] = hn;
    unsigned short hb = f2bf(hn);
    h1h[(size_t)b * kH + c] = hb;
    h1l[(size_t)b * kH + c] = f2bf(hn - bf2f(hb));
  }
  __syncthreads();

  // ---- B: hq = h1' @ W_hidd^T. 64 col-groups(8) x 16 k-groups(32) ----
  {
    int cg = tid & 63, kg = tid >> 6;   // kg 0..15
    int c0 = cg * 8;
    const unsigned short* w = whdbT + (size_t)(kg * 32) * kH + c0;
    float acc[8] = {};
    #pragma unroll 4
    for (int k = 0; k < 32; ++k) {
      union { uint4 u; unsigned short s[8]; } wu;
      wu.u = *(const uint4*)(w + (size_t)k * kH);
      float h = h1p[kg * 32 + k];
      #pragma unroll
      for (int j = 0; j < 8; ++j) acc[j] = fmaf(h, bf2f(wu.s[j]), acc[j]);
    }
    float* pp = &partbuf[kg * 512 + c0];
    #pragma unroll
    for (int j = 0; j < 8; ++j) pp[j] = acc[j];
  }
  __syncthreads();
  if (tid < 512) {
    float s = 0.f;
    #pragma unroll
    for (int g = 0; g < 16; ++g) s += partbuf[g * 512 + tid];
    hqs[tid] = s;
  }
  __syncthreads();

  // ---- C: attention scores (exp-tanh), 16 waves x 16 proposals ----
  {
    float hq8[8], aw[8];
    #pragma unroll
    for (int j = 0; j < 8; ++j) hq8[j] = hqs[lane * 8 + j];
    {
      float4 a0 = *(const float4*)(W_att + lane * 8);
      float4 a1 = *(const float4*)(W_att + lane * 8 + 4);
      aw[0] = a0.x; aw[1] = a0.y; aw[2] = a0.z; aw[3] = a0.w;
      aw[4] = a1.x; aw[5] = a1.y; aw[6] = a1.z; aw[7] = a1.w;
    }
    const unsigned short* fpb = fp + (size_t)b * kP * kH;
    int p0 = wv * 16;
    uint4 rv = *(const uint4*)(fpb + (size_t)p0 * kH + lane * 8);
    for (int p = p0; p < p0 + 16; ++p) {
      union { uint4 v; unsigned short s[8]; } u; u.v = rv;
      if (p + 1 < p0 + 16)
        rv = *(const uint4*)(fpb + (size_t)(p + 1) * kH + lane * 8);
      float sc = 0.f;
      #pragma unroll
      for (int j = 0; j < 8; ++j) {
        float f = __uint_as_float((unsigned)u.s[j] << 16);
        sc += aw[j] * ftanh(f + hq8[j]);
      }
      #pragma unroll
      for (int m = 32; m; m >>= 1) sc += __shfl_xor(sc, m, 64);
      if (lane == 0) scs[p] = sc;
    }
  }
  __syncthreads();

  // ---- D: softmax over 256 proposals ----
  {
    float sv = (tid < 256) ? scs[tid] : -1e30f;
    float mx = sv;
    #pragma unroll
    for (int m = 32; m; m >>= 1) mx = fmaxf(mx, __shfl_xor(mx, m, 64));
    if (lane == 0) red[wv] = mx;
    __syncthreads();
    float bm = red[0];
    #pragma unroll
    for (int i = 1; i < 16; ++i) bm = fmaxf(bm, red[i]);
    float ev = (tid < 256) ? fexp2((sv - bm) * 1.4426950408889634f) : 0.f;
    float sm = ev;
    #pragma unroll
    for (int m = 32; m; m >>= 1) sm += __shfl_xor(sm, m, 64);
    if (lane == 0) red2[wv] = sm;
    __syncthreads();
    float tot = 0.f;
    #pragma unroll
    for (int i = 0; i < 16; ++i) tot += red2[i];
    if (tid < 256) {
      float mk = ev * frcp(tot);
      scs[tid] = mk;
      mask_ws[(size_t)t * (kB * kP) + (size_t)b * kP + tid] = mk;
    }
  }
  __syncthreads();

  // ---- E: attended = mask @ c_feats, 8 proposal-groups x 32 ----
  {
    int c = tid & 127, q = tid >> 7;
    const float* cf = c_feats + ((size_t)b * kP + q * 32) * kC + c;
    const float* ms = scs + q * 32;
    float acc = 0.f;
    for (int p = 0; p < 32; ++p) acc = fmaf(ms[p], cf[(size_t)p * kC], acc);
    partbuf[q * 128 + c] = acc;
  }
  __syncthreads();
  if (tid < 128) {
    float s = 0.f;
    #pragma unroll
    for (int q = 0; q < 8; ++q) s += partbuf[q * 128 + tid];
    attl[tid] = s;
  }
  __syncthreads();

  // ---- F: lt1 = tanh(att@W_l1^T + h1'@W_l2^T) ----
  {
    if (tid < 512) {
      int cg = tid & 15, kg = tid >> 4;
      int c0 = cg * 8;
      const unsigned short* w = l2bt + (size_t)(kg * 16) * kC + c0;
      float acc[8] = {};
      for (int k = 0; k < 16; ++k) {
        union { uint4 u; unsigned short s[8]; } wu;
        wu.u = *(const uint4*)(w + (size_t)k * kC);
        float h = h1p[kg * 16 + k];
        #pragma unroll
        for (int j = 0; j < 8; ++j) acc[j] = fmaf(h, bf2f(wu.s[j]), acc[j]);
      }
      float* pp = &partbuf[kg * 128 + c0];
      #pragma unroll
      for (int j = 0; j < 8; ++j) pp[j] = acc[j];
    } else if (tid < 768) {
      int tt = tid - 512;
      int cg = tt & 15, kg = tt >> 4;
      int c0 = cg * 8;
      const unsigned short* w = l1bt + (size_t)(kg * 8) * kC + c0;
      float acc[8] = {};
      for (int k = 0; k < 8; ++k) {
        union { uint4 u; unsigned short s[8]; } wu;
        wu.u = *(const uint4*)(w + (size_t)k * kC);
        float a = attl[kg * 8 + k];
        #pragma unroll
        for (int j = 0; j < 8; ++j) acc[j] = fmaf(a, bf2f(wu.s[j]), acc[j]);
      }
      float* pp = &partbuf[4096 + kg * 128 + c0];
      #pragma unroll
      for (int j = 0; j < 8; ++j) pp[j] = acc[j];
    }
  }
  __syncthreads();
  if (tid < 128) {
    float s = 0.f;
    #pragma unroll
    for (int g = 0; g < 32; ++g) s += partbuf[g * 128 + tid];
    #pragma unroll
    for (int g = 0; g < 16; ++g) s += partbuf[4096 + g * 128 + tid];
    lt1[tid] = ftanh(s);
  }
  __syncthreads();

  // ---- G: llv = relu(lt1 @ W_l^T), 16 cg x 16 kg (k=8) ----
  if (tid < 256) {
    int cg = tid & 15, kg = tid >> 4;
    int c0 = cg * 8;
    const unsigned short* w = lbt + (size_t)(kg * 8) * kC + c0;
    float acc[8] = {};
    for (int k = 0; k < 8; ++k) {
      union { uint4 u; unsigned short s[8]; } wu;
      wu.u = *(const uint4*)(w + (size_t)k * kC);
      float l = lt1[kg * 8 + k];
      #pragma unroll
      for (int j = 0; j < 8; ++j) acc[j] = fmaf(l, bf2f(wu.s[j]), acc[j]);
    }
    float* pp = &partbuf[kg * 128 + c0];
    #pragma unroll
    for (int j = 0; j < 8; ++j) pp[j] = acc[j];
  }
  __syncthreads();
  if (tid < 128) {
    float s = 0.f;
    #pragma unroll
    for (int g = 0; g < 16; ++g) s += partbuf[g * 128 + tid];
    llv[tid] = fmaxf(s, 0.f);
  }
  __syncthreads();

  // ---- H: gx2 = llv @ W2_ih^T + b2. 192 cg(8) x 4 kg(32) ----
  if (tid < 768) {
    int cg = tid % 192, kg = tid / 192;
    int c0 = cg * 8;
    const unsigned short* w = iht2b + (size_t)(kg * 32) * kG + c0;
    float acc[8] = {};
    #pragma unroll 4
    for (int k = 0; k < 32; ++k) {
      union { uint4 u; unsigned short s[8]; } wu;
      wu.u = *(const uint4*)(w + (size_t)k * kG);
      float l = llv[kg * 32 + k];
      #pragma unroll
      for (int j = 0; j < 8; ++j) acc[j] = fmaf(l, bf2f(wu.s[j]), acc[j]);
    }
    float* pp = &partbuf[kg * 1536 + c0];
    #pragma unroll
    for (int j = 0; j < 8; ++j) pp[j] = acc[j];
  }
  __syncthreads();
  for (int c = tid; c < kG; c += 1024) {
    float s = b2_ih[c];
    #pragma unroll
    for (int g = 0; g < 4; ++g) s += partbuf[g * 1536 + c];
    gx2l[c] = s;
  }
  __syncthreads();
  if (tid < 512) {
    int c = tid;
    float ghr = gh2[(size_t)b * kG + c] + gh2[GPART + (size_t)b * kG + c];
    float ghz = gh2[(size_t)b * kG + 512 + c] + gh2[GPART + (size_t)b * kG + 512 + c];
    float ghn = gh2[(size_t)b * kG + 1024 + c] + gh2[GPART + (size_t)b * kG + 1024 + c];
    float rr = fsigm(gx2l[c] + ghr);
    float zz = fsigm(gx2l[512 + c] + ghz);
    float nn = ftanh(gx2l[1024 + c] + rr * ghn);
    float ho = h2[(size_t)b * kH + c];
    float hn = (1.f - zz) * nn + zz * ho;
    h2[(size_t)b * kH + c] = hn;
    h2p[c] = hn;
    unsigned short hb = f2bf(hn);
    unsigned short lb = f2bf(hn - bf2f(hb));
    h2h[(size_t)b * kH + c] = hb;
    h2l[(size_t)b * kH + c] = lb;
    size_t o = ((size_t)t * kB + b) * kH + c;
    h2all_h[o] = hb;
    h2all_l[o] = lb;
  }
  __syncthreads();

  // ---- I: next step's s-chain (s2 emitted hi/lo; gx1 moved to k_gh) ----
  if (t + 1 < kNS) {
    // I1: s1 = tanh(xw[t+1] + h2'@W_td1^T), 16 cg x 32 kg (k=16)
    if (tid < 512) {
      int cg = tid & 15, kg = tid >> 4;
      int c0 = cg * 8;
      const unsigned short* w = td1bt + (size_t)(kg * 16) * kC + c0;
      float acc[8] = {};
      for (int k = 0; k < 16; ++k) {
        union { uint4 u; unsigned short s[8]; } wu;
        wu.u = *(const uint4*)(w + (size_t)k * kC);
        float h = h2p[kg * 16 + k];
        #pragma unroll
        for (int j = 0; j < 8; ++j) acc[j] = fmaf(h, bf2f(wu.s[j]), acc[j]);
      }
      float* pp = &partbuf[kg * 128 + c0];
      #pragma unroll
      for (int j = 0; j < 8; ++j) pp[j] = acc[j];
    }
    __syncthreads();
    if (tid < 128) {
      float s = xw[((size_t)(t + 1) * kB + b) * kC + tid];
      #pragma unroll
      for (int g = 0; g < 32; ++g) s += partbuf[g * 128 + tid];
      s1l[tid] = ftanh(s);
    }
    __syncthreads();
    // I2: s2 = relu(s1 @ W_td^T) -> global hi/lo, 16 cg x 16 kg (k=8)
    if (tid < 256) {
      int cg = tid & 15, kg = tid >> 4;
      int c0 = cg * 8;
      const unsigned short* w = tdbt + (size_t)(kg * 8) * kC + c0;
      float acc[8] = {};
      for (int k = 0; k < 8; ++k) {
        union { uint4 u; unsigned short s[8]; } wu;
        wu.u = *(const uint4*)(w + (size_t)k * kC);
        float sv = s1l[kg * 8 + k];
        #pragma unroll
        for (int j = 0; j < 8; ++j) acc[j] = fmaf(sv, bf2f(wu.s[j]), acc[j]);
      }
      float* pp = &partbuf[kg * 128 + c0];
      #pragma unroll
      for (int j = 0; j < 8; ++j) pp[j] = acc[j];
    }
    __syncthreads();
    if (tid < 128) {
      float s = 0.f;
      #pragma unroll
      for (int g = 0; g < 16; ++g) s += partbuf[g * 128 + tid];
      s = fmaxf(s, 0.f);
      unsigned short hb = f2bf(s);
      s2h[(size_t)b * kC + tid] = hb;
      s2l[(size_t)b * kC + tid] = f2bf(s - bf2f(hb));
    }
  }
}

// ---------------- mask transpose via LDS: [t][b][p] -> out[b][p][t] ----------
__global__ __launch_bounds__(256) void k_atrans(
    const float* __restrict__ mws, float* __restrict__ attn_out) {
  __shared__ float tile[256][33];
  int pair0 = blockIdx.x * 256;     // 256 blocks cover 65536 (b,p) pairs
  int tid = threadIdx.x;
  #pragma unroll
  for (int t = 0; t < kNS; ++t)
    tile[tid][t] = mws[(size_t)t * (kB * kP) + pair0 + tid];
  __syncthreads();
  float* outb = attn_out + (size_t)pair0 * kNS;
  #pragma unroll
  for (int i = 0; i < kNS; ++i) {
    int g = i * 256 + tid;           // 0..7935 contiguous output floats
    int pr = g / 31, tt = g - pr * 31;
    outb[g] = tile[pr][tt];
  }
}

// ---------------- classifier: lang = h2_all @ W_cls^T + b_cls (MFMA, LDS) ----
__global__ __launch_bounds__(256) void k_cls(
    const unsigned short* __restrict__ Ah, const unsigned short* __restrict__ Al,
    const unsigned short* __restrict__ Wh,
    const float* __restrict__ bc, float* __restrict__ out) {
  __shared__ __align__(16) unsigned short sAh[4096], sAl[4096], sBh[4096];
  int m0 = blockIdx.x * 128, n0 = blockIdx.y * 128;
  f32x4 acc[4][4];
  #pragma unroll
  for (int i = 0; i < 4; ++i)
    #pragma unroll
    for (int j = 0; j < 4; ++j) acc[i][j] = (f32x4){0.f, 0.f, 0.f, 0.f};
  mm_tile_lds(Ah, Al, Wh, m0, n0, kH, 0, kH, kV - 1, acc, sAh, sAl, sBh);
  int lane = threadIdx.x & 63, wid = threadIdx.x >> 6;
  int wm = (wid >> 1) * 64, wn = (wid & 1) * 64;
  int r16 = lane & 15, kq = lane >> 4;
  #pragma unroll
  for (int i = 0; i < 4; ++i)
    #pragma unroll
    for (int j = 0; j < 4; ++j)
      #pragma unroll
      for (int r = 0; r < 4; ++r) {
        int m = m0 + wm + i * 16 + kq * 4 + r;
        int n = n0 + wn + j * 16 + r16;
        if (n < kV) {
          int tt = m >> 8, b = m & 255;
          out[(size_t)b * (kNS * kV) + (size_t)tt * kV + n] = acc[i][j][r] + bc[n];
        }
      }
}

}  // namespace

extern "C" void kernel_launch(void* const* d_in, const int* in_sizes, int n_in,
                              void* d_out, int out_size, void* d_ws,
                              size_t ws_size, hipStream_t stream) {
  (void)in_sizes; (void)n_in; (void)out_size; (void)ws_size;
  const float* word_embs = (const float*)d_in[0];
  const float* t_feat    = (const float*)d_in[1];
  const float* c_feats   = (const float*)d_in[2];
  const float* W_td1 = (const float*)d_in[4];
  const float* W_td2 = (const float*)d_in[5];
  const float* W_td3 = (const float*)d_in[6];
  const float* W_td  = (const float*)d_in[7];
  const float* W1_ih = (const float*)d_in[8];
  const float* W1_hh = (const float*)d_in[9];
  const float* b1_ih = (const float*)d_in[10];
  const float* b1_hh = (const float*)d_in[11];
  const float* W_feat = (const float*)d_in[12];
  const float* W_hidd = (const float*)d_in[13];
  const float* W_att  = (const float*)d_in[14];
  const float* W_l1 = (const float*)d_in[15];
  const float* W_l2 = (const float*)d_in[16];
  const float* W_l  = (const float*)d_in[17];
  const float* W2_ih = (const float*)d_in[18];
  const float* W2_hh = (const float*)d_in[19];
  const float* b2_ih = (const float*)d_in[20];
  const float* b2_hh = (const float*)d_in[21];
  const float* W_cls = (const float*)d_in[22];
  const float* b_cls = (const float*)d_in[23];

  float* lang = (float*)d_out;
  float* attn_out = lang + (size_t)kB * kNS * kV;
  // feat_proj (bf16, 64MB) lives in the lang_cap region of d_out — dead by
  // the time k_cls (the only writer of lang_cap) runs.
  unsigned short* fp = (unsigned short*)d_out;

  float* p = (float*)d_ws;
  float* h1 = p;      p += kB * kH;
  float* h2 = p;      p += kB * kH;
  float* td = p;      p += kB * kC;
  float* gx1 = p;     p += (size_t)kB * kG;
  float* gh1 = p;     p += (size_t)2 * kB * kG;   // 2 K-split partials
  float* gh2 = p;     p += (size_t)2 * kB * kG;
  float* mask_ws = p; p += (size_t)kNS * kB * kP;
  float* xw = p;      p += (size_t)kNS * kB * kC;
  float* td3t = p;    p += kE * 128;
  float* td1t = p;    p += kH * 128;
  float* tdt  = p;    p += 128 * 128;
  float* l1t  = p;    p += 128 * 128;
  float* l2t  = p;    p += kH * 128;
  float* lt   = p;    p += 128 * 128;
  float* iht2 = p;    p += 128 * kG;
  float* whd_t = p;   p += kH * kH;

  unsigned short* u = (unsigned short*)p;
  unsigned short* h1h = u;     u += kB * kH;
  unsigned short* h1l = u;     u += kB * kH;
  unsigned short* h2h = u;     u += kB * kH;
  unsigned short* h2l = u;     u += kB * kH;
  unsigned short* w1hh_h = u;  u += (size_t)kG * kH;
  unsigned short* w1hh_l = u;  u += (size_t)kG * kH;
  unsigned short* w2hh_h = u;  u += (size_t)kG * kH;
  unsigned short* w2hh_l = u;  u += (size_t)kG * kH;
  unsigned short* wc_h = u;    u += (size_t)kV * kH;
  unsigned short* wc_l = u;    u += (size_t)kV * kH;
  unsigned short* wf_h = u;    u += (size_t)kH * kC;
  unsigned short* wf_l = u;    u += (size_t)kH * kC;
  unsigned short* h2all_h = u; u += (size_t)kNS * kB * kH;
  unsigned short* h2all_l = u; u += (size_t)kNS * kB * kH;
  unsigned short* l1bt = u;    u += kC * kC;
  unsigned short* l2bt = u;    u += (size_t)kH * kC;
  unsigned short* lbt = u;     u += kC * kC;
  unsigned short* iht2b = u;   u += (size_t)kC * kG;
  unsigned short* whdbT = u;   u += (size_t)kH * kH;
  unsigned short* td1bt = u;   u += (size_t)kH * kC;
  unsigned short* tdbt = u;    u += kC * kC;
  unsigned short* w1ih_h = u;  u += (size_t)kG * kC;
  unsigned short* s2h = u;     u += kB * kC;
  unsigned short* s2l = u;     u += kB * kC;

  k_transpose<<<dim3(64, 9), 256, 0, stream>>>(
      W_td3, W_td1, W_td, W_l1, W_l2, W_l, W1_ih, W2_ih, W_hidd,
      td3t, td1t, tdt, l1t, l2t, lt, (float*)d_ws /*unused slot*/, iht2, whd_t);
  k_tobf16<<<dim3(96, 8), 256, 0, stream>>>(
      l1t, l2t, lt, iht2, whd_t, td1t, tdt, W1_ih,
      l1bt, l2bt, lbt, iht2b, whdbT, td1bt, tdbt, w1ih_h);
  k_split<<<dim3(256, 4), 256, 0, stream>>>(
      W1_hh, W2_hh, W_cls, W_feat,
      w1hh_h, w1hh_l, w2hh_h, w2hh_l, wc_h, wc_l, wf_h, wf_l);
  k_init<<<128, 256, 0, stream>>>(t_feat, W_td2, td, h1, h2,
                                  h1h, h1l, h2h, h2l);
  k_featproj<<<dim3(512, 4), 256, 0, stream>>>(c_feats, wf_h, fp);
  k_xw<<<dim3(64, kNS), 256, 0, stream>>>(word_embs, td3t, td, xw);
  k_prestep<<<256, 256, 0, stream>>>(xw, tdbt, s2h, s2l);

  for (int t = 0; t < kNS; ++t) {
    k_gh<<<120, 256, 0, stream>>>(h1h, h1l, h2h, h2l,
                                  w1hh_h, w2hh_h, b1_hh, b2_hh, gh1, gh2,
                                  s2h, s2l, w1ih_h, b1_ih, gx1);
    k_step2<<<256, 1024, 0, stream>>>(gx1, gh1, gh2, h1, h2,
                                      h1h, h1l, h2h, h2l, whdbT, W_att, fp,
                                      c_feats, l1bt, l2bt, lbt, iht2b, b2_ih,
                                      td1bt, tdbt, xw, s2h, s2l,
                                      h2all_h, h2all_l, mask_ws, t);
  }
  k_atrans<<<256, 256, 0, stream>>>(mask_ws, attn_out);
  k_cls<<<dim3(62, 27), 256, 0, stream>>>(h2all_h, h2all_l, wc_h,
                                          b_cls, lang);
}